// Round 1
// baseline (847.292 us; speedup 1.0000x reference)
//
#include <hip/hip_runtime.h>

// ---------------------------------------------------------------------------
// GCNEncoder: 3x GCNConv(128->128) + ReLU(2x) + global mean pool (64 graphs)
// Strategy:
//   - dinv (sym-norm) computed once; CSR-by-dst built once per launch.
//   - per layer: xw = h @ W (fp32, W in LDS), then CSR gather-aggregate
//     (register accum, no float atomics), fused bias + optional ReLU.
//   - mean pool exploits sorted `batch`: chunked register partial sums.
// ---------------------------------------------------------------------------

#define DFEAT 128

__global__ void deg_count(const int* __restrict__ dst, const float* __restrict__ ew,
                          float* __restrict__ deg, int* __restrict__ cnt, int E) {
    int e = blockIdx.x * 256 + threadIdx.x;
    if (e < E) {
        int d = dst[e];
        atomicAdd(&deg[d], ew[e]);
        atomicAdd(&cnt[d], 1);
    }
}

__global__ void dinv_k(float* __restrict__ degv, int n) {
    int i = blockIdx.x * 256 + threadIdx.x;
    if (i < n) {
        float d = degv[i] + 1.0f;  // + self-loop weight 1
        degv[i] = rsqrtf(d);       // d >= 1 > 0 always
    }
}

// Exclusive scan of cnt[n] -> row_ptr (within-block), blksum[b] = block total.
__global__ __launch_bounds__(256) void scan_block(const int* __restrict__ cnt,
                                                  int* __restrict__ excl,
                                                  int* __restrict__ blksum, int n) {
    int tid = threadIdx.x;
    int base = blockIdx.x * 1024 + tid * 4;
    int v0 = (base + 0 < n) ? cnt[base + 0] : 0;
    int v1 = (base + 1 < n) ? cnt[base + 1] : 0;
    int v2 = (base + 2 < n) ? cnt[base + 2] : 0;
    int v3 = (base + 3 < n) ? cnt[base + 3] : 0;
    int tsum = v0 + v1 + v2 + v3;
    int lane = tid & 63;
    int incl = tsum;
    #pragma unroll
    for (int off = 1; off < 64; off <<= 1) {
        int u = __shfl_up(incl, (unsigned)off, 64);
        if (lane >= off) incl += u;
    }
    __shared__ int wtot[4];
    int wave = tid >> 6;
    if (lane == 63) wtot[wave] = incl;
    __syncthreads();
    int woff = 0;
    for (int w = 0; w < wave; w++) woff += wtot[w];
    int texcl = woff + incl - tsum;
    if (base + 0 < n) excl[base + 0] = texcl;
    if (base + 1 < n) excl[base + 1] = texcl + v0;
    if (base + 2 < n) excl[base + 2] = texcl + v0 + v1;
    if (base + 3 < n) excl[base + 3] = texcl + v0 + v1 + v2;
    if (tid == 255) blksum[blockIdx.x] = woff + incl;  // block total
}

__global__ void scan_small(int* __restrict__ blksum, int nb) {
    int lane = threadIdx.x;
    int v = (lane < nb) ? blksum[lane] : 0;
    int incl = v;
    #pragma unroll
    for (int off = 1; off < 64; off <<= 1) {
        int u = __shfl_up(incl, (unsigned)off, 64);
        if (lane >= off) incl += u;
    }
    if (lane < nb) blksum[lane] = incl - v;  // exclusive
}

__global__ void scan_finish(int* __restrict__ row_ptr, int* __restrict__ cursor,
                            const int* __restrict__ blksum, int n, int E) {
    int i = blockIdx.x * 256 + threadIdx.x;
    if (i < n) {
        int r = row_ptr[i] + blksum[i >> 10];
        row_ptr[i] = r;
        cursor[i] = r;
    }
    if (i == 0) row_ptr[n] = E;
}

__global__ void fill_k(const int* __restrict__ src, const int* __restrict__ dst,
                       const float* __restrict__ ew, const float* __restrict__ dinv,
                       int* __restrict__ cursor, int* __restrict__ csr_src,
                       float* __restrict__ csr_norm, int E) {
    int e = blockIdx.x * 256 + threadIdx.x;
    if (e < E) {
        int d = dst[e], s = src[e];
        int p = atomicAdd(&cursor[d], 1);
        csr_src[p] = s;
        csr_norm[p] = dinv[s] * ew[e] * dinv[d];
    }
}

__device__ __forceinline__ void fma4(float4& acc, float a, const float4& w) {
    acc.x = fmaf(a, w.x, acc.x);
    acc.y = fmaf(a, w.y, acc.y);
    acc.z = fmaf(a, w.z, acc.z);
    acc.w = fmaf(a, w.w, acc.w);
}

// C[n,128] = A[n,128] @ W[128,128]; W staged in LDS (64 KB).
// Block = 256 threads -> 16 rows x 128 cols per block (2 rows x 4 cols/thread).
__global__ __launch_bounds__(256) void gemm128(const float* __restrict__ A,
                                               const float* __restrict__ W,
                                               float* __restrict__ C, int n) {
    __shared__ float Wl[DFEAT * DFEAT];
    for (int i = threadIdx.x * 4; i < DFEAT * DFEAT; i += 256 * 4) {
        *(float4*)&Wl[i] = *(const float4*)&W[i];
    }
    __syncthreads();
    int tc = (threadIdx.x & 31) << 2;   // col 0..124 step 4
    int tr = (threadIdx.x >> 5) << 1;   // row-in-tile 0,2,..,14
    int row = blockIdx.x * 16 + tr;
    if (row >= n) return;
    const float* a0 = A + (size_t)row * DFEAT;
    const float* a1 = a0 + DFEAT;
    float4 acc0 = make_float4(0.f, 0.f, 0.f, 0.f);
    float4 acc1 = make_float4(0.f, 0.f, 0.f, 0.f);
    #pragma unroll 4
    for (int k = 0; k < DFEAT; k += 4) {
        float4 av0 = *(const float4*)(a0 + k);
        float4 av1 = *(const float4*)(a1 + k);
        float4 w0 = *(float4*)&Wl[(k + 0) * DFEAT + tc];
        float4 w1 = *(float4*)&Wl[(k + 1) * DFEAT + tc];
        float4 w2 = *(float4*)&Wl[(k + 2) * DFEAT + tc];
        float4 w3 = *(float4*)&Wl[(k + 3) * DFEAT + tc];
        fma4(acc0, av0.x, w0); fma4(acc0, av0.y, w1);
        fma4(acc0, av0.z, w2); fma4(acc0, av0.w, w3);
        fma4(acc1, av1.x, w0); fma4(acc1, av1.y, w1);
        fma4(acc1, av1.z, w2); fma4(acc1, av1.w, w3);
    }
    *(float4*)&C[(size_t)row * DFEAT + tc] = acc0;
    *(float4*)&C[(size_t)(row + 1) * DFEAT + tc] = acc1;
}

// One wave per dst node; lane holds 2 features (float2).
// out[node] = sum_e norm[e]*xw[src[e]] + dinv[node]^2*xw[node] + bias (, ReLU)
__global__ __launch_bounds__(64) void agg_k(const float* __restrict__ xw,
                                            const int* __restrict__ row_ptr,
                                            const int* __restrict__ csr_src,
                                            const float* __restrict__ csr_norm,
                                            const float* __restrict__ dinv,
                                            const float* __restrict__ bias,
                                            float* __restrict__ out, int relu) {
    int node = blockIdx.x;
    int lane = threadIdx.x;
    const float2* xw2 = (const float2*)xw;
    float di = dinv[node];
    float2 selfv = xw2[(size_t)node * 64 + lane];
    float sc = di * di;
    float ax = sc * selfv.x, ay = sc * selfv.y;
    int e = row_ptr[node], end = row_ptr[node + 1];
    for (; e + 4 <= end; e += 4) {
        int s0 = csr_src[e + 0], s1 = csr_src[e + 1];
        int s2 = csr_src[e + 2], s3 = csr_src[e + 3];
        float w0 = csr_norm[e + 0], w1 = csr_norm[e + 1];
        float w2 = csr_norm[e + 2], w3 = csr_norm[e + 3];
        float2 v0 = xw2[(size_t)s0 * 64 + lane];
        float2 v1 = xw2[(size_t)s1 * 64 + lane];
        float2 v2 = xw2[(size_t)s2 * 64 + lane];
        float2 v3 = xw2[(size_t)s3 * 64 + lane];
        ax = fmaf(w0, v0.x, ax); ay = fmaf(w0, v0.y, ay);
        ax = fmaf(w1, v1.x, ax); ay = fmaf(w1, v1.y, ay);
        ax = fmaf(w2, v2.x, ax); ay = fmaf(w2, v2.y, ay);
        ax = fmaf(w3, v3.x, ax); ay = fmaf(w3, v3.y, ay);
    }
    for (; e < end; e++) {
        int s = csr_src[e];
        float w = csr_norm[e];
        float2 v = xw2[(size_t)s * 64 + lane];
        ax = fmaf(w, v.x, ax); ay = fmaf(w, v.y, ay);
    }
    float2 bv = ((const float2*)bias)[lane];
    ax += bv.x; ay += bv.y;
    if (relu) { ax = fmaxf(ax, 0.f); ay = fmaxf(ay, 0.f); }
    float2 o; o.x = ax; o.y = ay;
    ((float2*)out)[(size_t)node * 64 + lane] = o;
}

// batch is sorted: chunk of 64 nodes per block, 128 threads (one per feature).
// Also accumulates node counts per graph (thread 0).
__global__ __launch_bounds__(128) void pool_k(const float* __restrict__ h,
                                              const int* __restrict__ batch,
                                              float* __restrict__ out,
                                              float* __restrict__ pool_cnt, int n) {
    int j = threadIdx.x;
    int start = blockIdx.x * 64;
    if (start >= n) return;
    int end = start + 64; if (end > n) end = n;
    int g = batch[start];
    float acc = 0.f;
    float ccnt = 0.f;
    for (int i = start; i < end; i++) {
        int bi = batch[i];
        if (bi != g) {
            atomicAdd(&out[g * DFEAT + j], acc);
            if (j == 0) atomicAdd(&pool_cnt[g], ccnt);
            acc = 0.f; ccnt = 0.f; g = bi;
        }
        acc += h[(size_t)i * DFEAT + j];
        ccnt += 1.f;
    }
    atomicAdd(&out[g * DFEAT + j], acc);
    if (j == 0) atomicAdd(&pool_cnt[g], ccnt);
}

__global__ void div_k(float* __restrict__ out, const float* __restrict__ cnt) {
    int idx = blockIdx.x * 256 + threadIdx.x;
    if (idx < 64 * DFEAT) {
        float c = cnt[idx >> 7];
        out[idx] = out[idx] / fmaxf(c, 1.0f);
    }
}

extern "C" void kernel_launch(void* const* d_in, const int* in_sizes, int n_in,
                              void* d_out, int out_size, void* d_ws, size_t ws_size,
                              hipStream_t stream) {
    const float* x    = (const float*)d_in[0];
    const int*  eidx  = (const int*)d_in[1];
    const float* ew   = (const float*)d_in[2];
    const int*  batch = (const int*)d_in[3];
    const float* W0 = (const float*)d_in[4];
    const float* b0 = (const float*)d_in[5];
    const float* W1 = (const float*)d_in[6];
    const float* b1 = (const float*)d_in[7];
    const float* W2 = (const float*)d_in[8];
    const float* b2 = (const float*)d_in[9];
    float* out = (float*)d_out;

    const int N = in_sizes[0] / DFEAT;   // 50000
    const int E = in_sizes[2];           // 1600000
    const int* src = eidx;
    const int* dst = eidx + E;

    size_t off = 0;
    auto walloc = [&](size_t bytes) -> void* {
        void* p = (char*)d_ws + off;
        off += (bytes + 255) & ~(size_t)255;
        return p;
    };
    float* dinv     = (float*)walloc((size_t)N * 4);        // deg then dinv (in place)
    int*   cnt      = (int*)  walloc((size_t)N * 4);
    int*   row_ptr  = (int*)  walloc((size_t)(N + 1) * 4);
    int*   cursor   = (int*)  walloc((size_t)N * 4);
    int*   blksum   = (int*)  walloc(256 * 4);
    int*   csr_src  = (int*)  walloc((size_t)E * 4);
    float* csr_norm = (float*)walloc((size_t)E * 4);
    float* bufA     = (float*)walloc((size_t)N * DFEAT * 4);
    float* bufB     = (float*)walloc((size_t)N * DFEAT * 4);
    float* pool_cnt = (float*)walloc(64 * 4);

    hipMemsetAsync(dinv, 0, (size_t)N * 4, stream);
    hipMemsetAsync(cnt, 0, (size_t)N * 4, stream);
    hipMemsetAsync(out, 0, (size_t)64 * DFEAT * 4, stream);
    hipMemsetAsync(pool_cnt, 0, 64 * 4, stream);

    int gE = (E + 255) / 256;
    int gN = (N + 255) / 256;
    int nblk = (N + 1023) / 1024;

    deg_count<<<gE, 256, 0, stream>>>(dst, ew, dinv, cnt, E);
    dinv_k<<<gN, 256, 0, stream>>>(dinv, N);
    scan_block<<<nblk, 256, 0, stream>>>(cnt, row_ptr, blksum, N);
    scan_small<<<1, 64, 0, stream>>>(blksum, nblk);
    scan_finish<<<gN, 256, 0, stream>>>(row_ptr, cursor, blksum, N, E);
    fill_k<<<gE, 256, 0, stream>>>(src, dst, ew, dinv, cursor, csr_src, csr_norm, E);

    int gG = (N + 15) / 16;
    // layer 0: x -> bufA (xw) -> bufB (h0, relu)
    gemm128<<<gG, 256, 0, stream>>>(x, W0, bufA, N);
    agg_k<<<N, 64, 0, stream>>>(bufA, row_ptr, csr_src, csr_norm, dinv, b0, bufB, 1);
    // layer 1: bufB -> bufA -> bufB (h1, relu)
    gemm128<<<gG, 256, 0, stream>>>(bufB, W1, bufA, N);
    agg_k<<<N, 64, 0, stream>>>(bufA, row_ptr, csr_src, csr_norm, dinv, b1, bufB, 1);
    // layer 2: bufB -> bufA -> bufB (h2, no relu)
    gemm128<<<gG, 256, 0, stream>>>(bufB, W2, bufA, N);
    agg_k<<<N, 64, 0, stream>>>(bufA, row_ptr, csr_src, csr_norm, dinv, b2, bufB, 0);

    pool_k<<<(N + 63) / 64, 128, 0, stream>>>(bufB, batch, out, pool_cnt, N);
    div_k<<<32, 256, 0, stream>>>(out, pool_cnt);
}

// Round 2
// 694.137 us; speedup vs baseline: 1.2206x; 1.2206x over previous
//
#include <hip/hip_runtime.h>

// ---------------------------------------------------------------------------
// GCNEncoder: 3x GCNConv(128->128) + ReLU(2x) + global mean pool (64 graphs)
//   - ONE packed 64-bit atomic per edge builds {count, deg} AND returns the
//     edge's within-node rank -> CSR fill needs no atomics at all.
//   - CSR entries packed int2{src, norm} (one 8B scattered write / edge).
//   - per layer: xw = h @ W (fp32, W in LDS) then CSR register-accum gather,
//     fused self-loop + bias + optional ReLU.
//   - mean pool exploits sorted `batch`.
// ---------------------------------------------------------------------------

#define DFEAT 128

// Pass 1: packed atomic. high32 = edge count, low32 = sum(ew) in 2^-24 fixed pt.
// Returned old count = this edge's rank within its dst node's adjacency list.
__global__ void pass1_k(const int* __restrict__ dst, const float* __restrict__ ew,
                        unsigned long long* __restrict__ degcnt,
                        int* __restrict__ rank, int E) {
    int e = blockIdx.x * 256 + threadIdx.x;
    if (e < E) {
        int d = dst[e];
        unsigned int fx = (unsigned int)(ew[e] * 16777216.0f);  // 2^24
        unsigned long long inc = (1ULL << 32) | (unsigned long long)fx;
        unsigned long long old = atomicAdd(&degcnt[d], inc);
        rank[e] = (int)(old >> 32);
    }
}

__global__ void dinv_cnt_k(const unsigned long long* __restrict__ degcnt,
                           float* __restrict__ dinv, int* __restrict__ cnt, int n) {
    int i = blockIdx.x * 256 + threadIdx.x;
    if (i < n) {
        unsigned long long p = degcnt[i];
        float deg = (float)((double)(p & 0xffffffffULL) * (1.0 / 16777216.0)) + 1.0f;
        dinv[i] = rsqrtf(deg);   // deg >= 1 always (self-loop)
        cnt[i] = (int)(p >> 32);
    }
}

// Exclusive scan of cnt[n] -> row_ptr (within-block), blksum[b] = block total.
__global__ __launch_bounds__(256) void scan_block(const int* __restrict__ cnt,
                                                  int* __restrict__ excl,
                                                  int* __restrict__ blksum, int n) {
    int tid = threadIdx.x;
    int base = blockIdx.x * 1024 + tid * 4;
    int v0 = (base + 0 < n) ? cnt[base + 0] : 0;
    int v1 = (base + 1 < n) ? cnt[base + 1] : 0;
    int v2 = (base + 2 < n) ? cnt[base + 2] : 0;
    int v3 = (base + 3 < n) ? cnt[base + 3] : 0;
    int tsum = v0 + v1 + v2 + v3;
    int lane = tid & 63;
    int incl = tsum;
    #pragma unroll
    for (int off = 1; off < 64; off <<= 1) {
        int u = __shfl_up(incl, (unsigned)off, 64);
        if (lane >= off) incl += u;
    }
    __shared__ int wtot[4];
    int wave = tid >> 6;
    if (lane == 63) wtot[wave] = incl;
    __syncthreads();
    int woff = 0;
    for (int w = 0; w < wave; w++) woff += wtot[w];
    int texcl = woff + incl - tsum;
    if (base + 0 < n) excl[base + 0] = texcl;
    if (base + 1 < n) excl[base + 1] = texcl + v0;
    if (base + 2 < n) excl[base + 2] = texcl + v0 + v1;
    if (base + 3 < n) excl[base + 3] = texcl + v0 + v1 + v2;
    if (tid == 255) blksum[blockIdx.x] = woff + incl;  // block total
}

__global__ void scan_small(int* __restrict__ blksum, int nb) {
    int lane = threadIdx.x;
    int v = (lane < nb) ? blksum[lane] : 0;
    int incl = v;
    #pragma unroll
    for (int off = 1; off < 64; off <<= 1) {
        int u = __shfl_up(incl, (unsigned)off, 64);
        if (lane >= off) incl += u;
    }
    if (lane < nb) blksum[lane] = incl - v;  // exclusive
}

__global__ void scan_finish(int* __restrict__ row_ptr,
                            const int* __restrict__ blksum, int n, int E) {
    int i = blockIdx.x * 256 + threadIdx.x;
    if (i < n) row_ptr[i] += blksum[i >> 10];
    if (i == 0) row_ptr[n] = E;
}

// Pass 2: no atomics. pos = row_ptr[dst] + rank. One 8B scattered write.
__global__ void fill2_k(const int* __restrict__ src, const int* __restrict__ dst,
                        const float* __restrict__ ew, const int* __restrict__ rank,
                        const int* __restrict__ row_ptr, const float* __restrict__ dinv,
                        int2* __restrict__ csr, int E) {
    int e = blockIdx.x * 256 + threadIdx.x;
    if (e < E) {
        int d = dst[e], s = src[e];
        int pos = row_ptr[d] + rank[e];
        float nm = dinv[s] * ew[e] * dinv[d];
        csr[pos] = make_int2(s, __float_as_int(nm));
    }
}

__device__ __forceinline__ void fma4(float4& acc, float a, const float4& w) {
    acc.x = fmaf(a, w.x, acc.x);
    acc.y = fmaf(a, w.y, acc.y);
    acc.z = fmaf(a, w.z, acc.z);
    acc.w = fmaf(a, w.w, acc.w);
}

// C[n,128] = A[n,128] @ W[128,128]; W staged in LDS (64 KB).
__global__ __launch_bounds__(256) void gemm128(const float* __restrict__ A,
                                               const float* __restrict__ W,
                                               float* __restrict__ C, int n) {
    __shared__ float Wl[DFEAT * DFEAT];
    for (int i = threadIdx.x * 4; i < DFEAT * DFEAT; i += 256 * 4) {
        *(float4*)&Wl[i] = *(const float4*)&W[i];
    }
    __syncthreads();
    int tc = (threadIdx.x & 31) << 2;   // col 0..124 step 4
    int tr = (threadIdx.x >> 5) << 1;   // row-in-tile 0,2,..,14
    int row = blockIdx.x * 16 + tr;
    if (row >= n) return;
    const float* a0 = A + (size_t)row * DFEAT;
    const float* a1 = a0 + DFEAT;
    float4 acc0 = make_float4(0.f, 0.f, 0.f, 0.f);
    float4 acc1 = make_float4(0.f, 0.f, 0.f, 0.f);
    #pragma unroll 4
    for (int k = 0; k < DFEAT; k += 4) {
        float4 av0 = *(const float4*)(a0 + k);
        float4 av1 = *(const float4*)(a1 + k);
        float4 w0 = *(float4*)&Wl[(k + 0) * DFEAT + tc];
        float4 w1 = *(float4*)&Wl[(k + 1) * DFEAT + tc];
        float4 w2 = *(float4*)&Wl[(k + 2) * DFEAT + tc];
        float4 w3 = *(float4*)&Wl[(k + 3) * DFEAT + tc];
        fma4(acc0, av0.x, w0); fma4(acc0, av0.y, w1);
        fma4(acc0, av0.z, w2); fma4(acc0, av0.w, w3);
        fma4(acc1, av1.x, w0); fma4(acc1, av1.y, w1);
        fma4(acc1, av1.z, w2); fma4(acc1, av1.w, w3);
    }
    *(float4*)&C[(size_t)row * DFEAT + tc] = acc0;
    *(float4*)&C[(size_t)(row + 1) * DFEAT + tc] = acc1;
}

// 4 nodes per 256-thread block (one wave each); lane holds 2 features.
// out[node] = sum_e norm[e]*xw[src[e]] + dinv[node]^2*xw[node] + bias (, ReLU)
__global__ __launch_bounds__(256) void agg_k(const float* __restrict__ xw,
                                             const int* __restrict__ row_ptr,
                                             const int2* __restrict__ csr,
                                             const float* __restrict__ dinv,
                                             const float* __restrict__ bias,
                                             float* __restrict__ out, int relu, int n) {
    int node = blockIdx.x * 4 + (threadIdx.x >> 6);
    if (node >= n) return;
    int lane = threadIdx.x & 63;
    const float2* xw2 = (const float2*)xw;
    float di = dinv[node];
    float2 selfv = xw2[(size_t)node * 64 + lane];
    float sc = di * di;
    float ax = sc * selfv.x, ay = sc * selfv.y;
    int e = row_ptr[node], end = row_ptr[node + 1];
    for (; e + 4 <= end; e += 4) {
        int2 c0 = csr[e + 0], c1 = csr[e + 1];
        int2 c2 = csr[e + 2], c3 = csr[e + 3];
        float2 v0 = xw2[(size_t)c0.x * 64 + lane];
        float2 v1 = xw2[(size_t)c1.x * 64 + lane];
        float2 v2 = xw2[(size_t)c2.x * 64 + lane];
        float2 v3 = xw2[(size_t)c3.x * 64 + lane];
        float w0 = __int_as_float(c0.y), w1 = __int_as_float(c1.y);
        float w2 = __int_as_float(c2.y), w3 = __int_as_float(c3.y);
        ax = fmaf(w0, v0.x, ax); ay = fmaf(w0, v0.y, ay);
        ax = fmaf(w1, v1.x, ax); ay = fmaf(w1, v1.y, ay);
        ax = fmaf(w2, v2.x, ax); ay = fmaf(w2, v2.y, ay);
        ax = fmaf(w3, v3.x, ax); ay = fmaf(w3, v3.y, ay);
    }
    for (; e < end; e++) {
        int2 c = csr[e];
        float w = __int_as_float(c.y);
        float2 v = xw2[(size_t)c.x * 64 + lane];
        ax = fmaf(w, v.x, ax); ay = fmaf(w, v.y, ay);
    }
    float2 bv = ((const float2*)bias)[lane];
    ax += bv.x; ay += bv.y;
    if (relu) { ax = fmaxf(ax, 0.f); ay = fmaxf(ay, 0.f); }
    float2 o; o.x = ax; o.y = ay;
    ((float2*)out)[(size_t)node * 64 + lane] = o;
}

// batch is sorted: chunk of 64 nodes per block, 128 threads (one per feature).
__global__ __launch_bounds__(128) void pool_k(const float* __restrict__ h,
                                              const int* __restrict__ batch,
                                              float* __restrict__ out,
                                              float* __restrict__ pool_cnt, int n) {
    int j = threadIdx.x;
    int start = blockIdx.x * 64;
    if (start >= n) return;
    int end = start + 64; if (end > n) end = n;
    int g = batch[start];
    float acc = 0.f;
    float ccnt = 0.f;
    for (int i = start; i < end; i++) {
        int bi = batch[i];
        if (bi != g) {
            atomicAdd(&out[g * DFEAT + j], acc);
            if (j == 0) atomicAdd(&pool_cnt[g], ccnt);
            acc = 0.f; ccnt = 0.f; g = bi;
        }
        acc += h[(size_t)i * DFEAT + j];
        ccnt += 1.f;
    }
    atomicAdd(&out[g * DFEAT + j], acc);
    if (j == 0) atomicAdd(&pool_cnt[g], ccnt);
}

__global__ void div_k(float* __restrict__ out, const float* __restrict__ cnt) {
    int idx = blockIdx.x * 256 + threadIdx.x;
    if (idx < 64 * DFEAT) {
        float c = cnt[idx >> 7];
        out[idx] = out[idx] / fmaxf(c, 1.0f);
    }
}

extern "C" void kernel_launch(void* const* d_in, const int* in_sizes, int n_in,
                              void* d_out, int out_size, void* d_ws, size_t ws_size,
                              hipStream_t stream) {
    const float* x    = (const float*)d_in[0];
    const int*  eidx  = (const int*)d_in[1];
    const float* ew   = (const float*)d_in[2];
    const int*  batch = (const int*)d_in[3];
    const float* W0 = (const float*)d_in[4];
    const float* b0 = (const float*)d_in[5];
    const float* W1 = (const float*)d_in[6];
    const float* b1 = (const float*)d_in[7];
    const float* W2 = (const float*)d_in[8];
    const float* b2 = (const float*)d_in[9];
    float* out = (float*)d_out;

    const int N = in_sizes[0] / DFEAT;   // 50000
    const int E = in_sizes[2];           // 1600000
    const int* src = eidx;
    const int* dst = eidx + E;

    size_t off = 0;
    auto walloc = [&](size_t bytes) -> void* {
        void* p = (char*)d_ws + off;
        off += (bytes + 255) & ~(size_t)255;
        return p;
    };
    float* dinv     = (float*)walloc((size_t)N * 4);
    int*   cnt      = (int*)  walloc((size_t)N * 4);
    int*   row_ptr  = (int*)  walloc((size_t)(N + 1) * 4);
    int*   blksum   = (int*)  walloc(256 * 4);
    int2*  csr      = (int2*) walloc((size_t)E * 8);
    float* bufA     = (float*)walloc((size_t)N * DFEAT * 4);
    float* bufB     = (float*)walloc((size_t)N * DFEAT * 4);
    float* pool_cnt = (float*)walloc(64 * 4);
    // rank + degcnt alias into bufA's region: both are dead before gemm/agg
    // first touch bufA (rank: E*4 = 6.4MB, degcnt: N*8 = 0.4MB; bufA = 25.6MB)
    int* rank = (int*)bufA;
    unsigned long long* degcnt =
        (unsigned long long*)((char*)bufA + (((size_t)E * 4 + 255) & ~(size_t)255));

    hipMemsetAsync(degcnt, 0, (size_t)N * 8, stream);
    hipMemsetAsync(out, 0, (size_t)64 * DFEAT * 4, stream);
    hipMemsetAsync(pool_cnt, 0, 64 * 4, stream);

    int gE = (E + 255) / 256;
    int gN = (N + 255) / 256;
    int nblk = (N + 1023) / 1024;

    pass1_k<<<gE, 256, 0, stream>>>(dst, ew, degcnt, rank, E);
    dinv_cnt_k<<<gN, 256, 0, stream>>>(degcnt, dinv, cnt, N);
    scan_block<<<nblk, 256, 0, stream>>>(cnt, row_ptr, blksum, N);
    scan_small<<<1, 64, 0, stream>>>(blksum, nblk);
    scan_finish<<<gN, 256, 0, stream>>>(row_ptr, blksum, N, E);
    fill2_k<<<gE, 256, 0, stream>>>(src, dst, ew, rank, row_ptr, dinv, csr, E);

    int gG = (N + 15) / 16;
    int gA = (N + 3) / 4;
    // layer 0: x -> bufA (xw) -> bufB (h0, relu)
    gemm128<<<gG, 256, 0, stream>>>(x, W0, bufA, N);
    agg_k<<<gA, 256, 0, stream>>>(bufA, row_ptr, csr, dinv, b0, bufB, 1, N);
    // layer 1: bufB -> bufA -> bufB (h1, relu)
    gemm128<<<gG, 256, 0, stream>>>(bufB, W1, bufA, N);
    agg_k<<<gA, 256, 0, stream>>>(bufA, row_ptr, csr, dinv, b1, bufB, 1, N);
    // layer 2: bufB -> bufA -> bufB (h2, no relu)
    gemm128<<<gG, 256, 0, stream>>>(bufB, W2, bufA, N);
    agg_k<<<gA, 256, 0, stream>>>(bufA, row_ptr, csr, dinv, b2, bufB, 0, N);

    pool_k<<<(N + 63) / 64, 128, 0, stream>>>(bufB, batch, out, pool_cnt, N);
    div_k<<<32, 256, 0, stream>>>(out, pool_cnt);
}

// Round 3
// 558.580 us; speedup vs baseline: 1.5169x; 1.2427x over previous
//
#include <hip/hip_runtime.h>
#include <hip/hip_fp16.h>

// ---------------------------------------------------------------------------
// GCNEncoder: 3x GCNConv(128->128) + ReLU(2x) + global mean pool (64 graphs)
//   - ONE packed 64-bit atomic per edge builds {count, deg} AND returns the
//     edge's within-node rank -> CSR fill needs no atomics at all.
//   - CSR entries packed int2{src, norm}.
//   - xw (post-GEMM activations) stored FP16: halves the gather traffic in
//     agg_k, which is the dominant cost (L2-miss-traffic bound). fp32 accum.
//   - mean pool exploits sorted `batch`.
// ---------------------------------------------------------------------------

#define DFEAT 128

// Pass 1: packed atomic. high32 = edge count, low32 = sum(ew) in 2^-24 fixed pt.
// Returned old count = this edge's rank within its dst node's adjacency list.
__global__ void pass1_k(const int* __restrict__ dst, const float* __restrict__ ew,
                        unsigned long long* __restrict__ degcnt,
                        int* __restrict__ rank, int E) {
    int e = blockIdx.x * 256 + threadIdx.x;
    if (e < E) {
        int d = dst[e];
        unsigned int fx = (unsigned int)(ew[e] * 16777216.0f);  // 2^24
        unsigned long long inc = (1ULL << 32) | (unsigned long long)fx;
        unsigned long long old = atomicAdd(&degcnt[d], inc);
        rank[e] = (int)(old >> 32);
    }
}

// Fused: unpack degcnt -> dinv, and block-level exclusive scan of counts.
__global__ __launch_bounds__(256) void scan_block(const unsigned long long* __restrict__ degcnt,
                                                  float* __restrict__ dinv,
                                                  int* __restrict__ excl,
                                                  int* __restrict__ blksum, int n) {
    int tid = threadIdx.x;
    int base = blockIdx.x * 1024 + tid * 4;
    int v0 = 0, v1 = 0, v2 = 0, v3 = 0;
    #define UNPACK(K, VK)                                                        \
        if (base + K < n) {                                                      \
            unsigned long long p = degcnt[base + K];                             \
            float deg = (float)((p & 0xffffffffULL) * (1.0f / 16777216.0f)) + 1.0f; \
            dinv[base + K] = rsqrtf(deg);                                        \
            VK = (int)(p >> 32);                                                 \
        }
    UNPACK(0, v0) UNPACK(1, v1) UNPACK(2, v2) UNPACK(3, v3)
    #undef UNPACK
    int tsum = v0 + v1 + v2 + v3;
    int lane = tid & 63;
    int incl = tsum;
    #pragma unroll
    for (int off = 1; off < 64; off <<= 1) {
        int u = __shfl_up(incl, (unsigned)off, 64);
        if (lane >= off) incl += u;
    }
    __shared__ int wtot[4];
    int wave = tid >> 6;
    if (lane == 63) wtot[wave] = incl;
    __syncthreads();
    int woff = 0;
    for (int w = 0; w < wave; w++) woff += wtot[w];
    int texcl = woff + incl - tsum;
    if (base + 0 < n) excl[base + 0] = texcl;
    if (base + 1 < n) excl[base + 1] = texcl + v0;
    if (base + 2 < n) excl[base + 2] = texcl + v0 + v1;
    if (base + 3 < n) excl[base + 3] = texcl + v0 + v1 + v2;
    if (tid == 255) blksum[blockIdx.x] = woff + incl;  // block total
}

__global__ void scan_small(int* __restrict__ blksum, int nb) {
    int lane = threadIdx.x;
    int v = (lane < nb) ? blksum[lane] : 0;
    int incl = v;
    #pragma unroll
    for (int off = 1; off < 64; off <<= 1) {
        int u = __shfl_up(incl, (unsigned)off, 64);
        if (lane >= off) incl += u;
    }
    if (lane < nb) blksum[lane] = incl - v;  // exclusive
}

__global__ void scan_finish(int* __restrict__ row_ptr,
                            const int* __restrict__ blksum, int n, int E) {
    int i = blockIdx.x * 256 + threadIdx.x;
    if (i < n) row_ptr[i] += blksum[i >> 10];
    if (i == 0) row_ptr[n] = E;
}

// Pass 2: no atomics. pos = row_ptr[dst] + rank. One 8B scattered write.
__global__ void fill2_k(const int* __restrict__ src, const int* __restrict__ dst,
                        const float* __restrict__ ew, const int* __restrict__ rank,
                        const int* __restrict__ row_ptr, const float* __restrict__ dinv,
                        int2* __restrict__ csr, int E) {
    int e = blockIdx.x * 256 + threadIdx.x;
    if (e < E) {
        int d = dst[e], s = src[e];
        int pos = row_ptr[d] + rank[e];
        float nm = dinv[s] * ew[e] * dinv[d];
        csr[pos] = make_int2(s, __float_as_int(nm));
    }
}

__device__ __forceinline__ void fma4(float4& acc, float a, const float4& w) {
    acc.x = fmaf(a, w.x, acc.x);
    acc.y = fmaf(a, w.y, acc.y);
    acc.z = fmaf(a, w.z, acc.z);
    acc.w = fmaf(a, w.w, acc.w);
}

// C[n,128] = A[n,128] @ W[128,128]; W staged in LDS (64 KB). Output FP16.
__global__ __launch_bounds__(256) void gemm128(const float* __restrict__ A,
                                               const float* __restrict__ W,
                                               __half* __restrict__ C, int n) {
    __shared__ float Wl[DFEAT * DFEAT];
    for (int i = threadIdx.x * 4; i < DFEAT * DFEAT; i += 256 * 4) {
        *(float4*)&Wl[i] = *(const float4*)&W[i];
    }
    __syncthreads();
    int tc = (threadIdx.x & 31) << 2;   // col 0..124 step 4
    int tr = (threadIdx.x >> 5) << 1;   // row-in-tile 0,2,..,14
    int row = blockIdx.x * 16 + tr;
    if (row >= n) return;
    const float* a0 = A + (size_t)row * DFEAT;
    const float* a1 = a0 + DFEAT;
    float4 acc0 = make_float4(0.f, 0.f, 0.f, 0.f);
    float4 acc1 = make_float4(0.f, 0.f, 0.f, 0.f);
    #pragma unroll 4
    for (int k = 0; k < DFEAT; k += 4) {
        float4 av0 = *(const float4*)(a0 + k);
        float4 av1 = *(const float4*)(a1 + k);
        float4 w0 = *(float4*)&Wl[(k + 0) * DFEAT + tc];
        float4 w1 = *(float4*)&Wl[(k + 1) * DFEAT + tc];
        float4 w2 = *(float4*)&Wl[(k + 2) * DFEAT + tc];
        float4 w3 = *(float4*)&Wl[(k + 3) * DFEAT + tc];
        fma4(acc0, av0.x, w0); fma4(acc0, av0.y, w1);
        fma4(acc0, av0.z, w2); fma4(acc0, av0.w, w3);
        fma4(acc1, av1.x, w0); fma4(acc1, av1.y, w1);
        fma4(acc1, av1.z, w2); fma4(acc1, av1.w, w3);
    }
    __half2 p0 = __floats2half2_rn(acc0.x, acc0.y);
    __half2 p1 = __floats2half2_rn(acc0.z, acc0.w);
    __half2 q0 = __floats2half2_rn(acc1.x, acc1.y);
    __half2 q1 = __floats2half2_rn(acc1.z, acc1.w);
    uint2 st0; st0.x = *(unsigned int*)&p0; st0.y = *(unsigned int*)&p1;
    uint2 st1; st1.x = *(unsigned int*)&q0; st1.y = *(unsigned int*)&q1;
    *(uint2*)&C[(size_t)row * DFEAT + tc] = st0;
    *(uint2*)&C[(size_t)(row + 1) * DFEAT + tc] = st1;
}

// 4 nodes per 256-thread block (one wave each); lane holds 2 fp16 features.
// out[node] = sum_e norm[e]*xw[src[e]] + dinv[node]^2*xw[node] + bias (, ReLU)
__global__ __launch_bounds__(256) void agg_k(const __half2* __restrict__ xw2,
                                             const int* __restrict__ row_ptr,
                                             const int2* __restrict__ csr,
                                             const float* __restrict__ dinv,
                                             const float* __restrict__ bias,
                                             float* __restrict__ out, int relu, int n) {
    int node = blockIdx.x * 4 + (threadIdx.x >> 6);
    if (node >= n) return;
    int lane = threadIdx.x & 63;
    float di = dinv[node];
    float2 selfv = __half22float2(xw2[(size_t)node * 64 + lane]);
    float sc = di * di;
    float ax = sc * selfv.x, ay = sc * selfv.y;
    int e = row_ptr[node], end = row_ptr[node + 1];
    for (; e + 4 <= end; e += 4) {
        int2 c0 = csr[e + 0], c1 = csr[e + 1];
        int2 c2 = csr[e + 2], c3 = csr[e + 3];
        float2 v0 = __half22float2(xw2[(size_t)c0.x * 64 + lane]);
        float2 v1 = __half22float2(xw2[(size_t)c1.x * 64 + lane]);
        float2 v2 = __half22float2(xw2[(size_t)c2.x * 64 + lane]);
        float2 v3 = __half22float2(xw2[(size_t)c3.x * 64 + lane]);
        float w0 = __int_as_float(c0.y), w1 = __int_as_float(c1.y);
        float w2 = __int_as_float(c2.y), w3 = __int_as_float(c3.y);
        ax = fmaf(w0, v0.x, ax); ay = fmaf(w0, v0.y, ay);
        ax = fmaf(w1, v1.x, ax); ay = fmaf(w1, v1.y, ay);
        ax = fmaf(w2, v2.x, ax); ay = fmaf(w2, v2.y, ay);
        ax = fmaf(w3, v3.x, ax); ay = fmaf(w3, v3.y, ay);
    }
    for (; e < end; e++) {
        int2 c = csr[e];
        float w = __int_as_float(c.y);
        float2 v = __half22float2(xw2[(size_t)c.x * 64 + lane]);
        ax = fmaf(w, v.x, ax); ay = fmaf(w, v.y, ay);
    }
    float2 bv = ((const float2*)bias)[lane];
    ax += bv.x; ay += bv.y;
    if (relu) { ax = fmaxf(ax, 0.f); ay = fmaxf(ay, 0.f); }
    float2 o; o.x = ax; o.y = ay;
    ((float2*)out)[(size_t)node * 64 + lane] = o;
}

// batch is sorted: chunk of 64 nodes per block, 128 threads (one per feature).
__global__ __launch_bounds__(128) void pool_k(const float* __restrict__ h,
                                              const int* __restrict__ batch,
                                              float* __restrict__ out,
                                              float* __restrict__ pool_cnt, int n) {
    int j = threadIdx.x;
    int start = blockIdx.x * 64;
    if (start >= n) return;
    int end = start + 64; if (end > n) end = n;
    int g = batch[start];
    float acc = 0.f;
    float ccnt = 0.f;
    for (int i = start; i < end; i++) {
        int bi = batch[i];
        if (bi != g) {
            atomicAdd(&out[g * DFEAT + j], acc);
            if (j == 0) atomicAdd(&pool_cnt[g], ccnt);
            acc = 0.f; ccnt = 0.f; g = bi;
        }
        acc += h[(size_t)i * DFEAT + j];
        ccnt += 1.f;
    }
    atomicAdd(&out[g * DFEAT + j], acc);
    if (j == 0) atomicAdd(&pool_cnt[g], ccnt);
}

__global__ void div_k(float* __restrict__ out, const float* __restrict__ cnt) {
    int idx = blockIdx.x * 256 + threadIdx.x;
    if (idx < 64 * DFEAT) {
        float c = cnt[idx >> 7];
        out[idx] = out[idx] / fmaxf(c, 1.0f);
    }
}

extern "C" void kernel_launch(void* const* d_in, const int* in_sizes, int n_in,
                              void* d_out, int out_size, void* d_ws, size_t ws_size,
                              hipStream_t stream) {
    const float* x    = (const float*)d_in[0];
    const int*  eidx  = (const int*)d_in[1];
    const float* ew   = (const float*)d_in[2];
    const int*  batch = (const int*)d_in[3];
    const float* W0 = (const float*)d_in[4];
    const float* b0 = (const float*)d_in[5];
    const float* W1 = (const float*)d_in[6];
    const float* b1 = (const float*)d_in[7];
    const float* W2 = (const float*)d_in[8];
    const float* b2 = (const float*)d_in[9];
    float* out = (float*)d_out;

    const int N = in_sizes[0] / DFEAT;   // 50000
    const int E = in_sizes[2];           // 1600000
    const int* src = eidx;
    const int* dst = eidx + E;

    size_t off = 0;
    auto walloc = [&](size_t bytes) -> void* {
        void* p = (char*)d_ws + off;
        off += (bytes + 255) & ~(size_t)255;
        return p;
    };
    float* dinv     = (float*)walloc((size_t)N * 4);
    int*   row_ptr  = (int*)  walloc((size_t)(N + 1) * 4);
    int*   blksum   = (int*)  walloc(256 * 4);
    int2*  csr      = (int2*) walloc((size_t)E * 8);
    __half* xwH     = (__half*)walloc((size_t)N * DFEAT * 2);
    float* h        = (float*)walloc((size_t)N * DFEAT * 4);
    float* pool_cnt = (float*)walloc(64 * 4);
    // rank + degcnt alias into xwH's region: both are dead before gemm0
    // first touches xwH (rank: E*4 = 6.4MB, degcnt: N*8 = 0.4MB; xwH = 12.8MB)
    int* rank = (int*)xwH;
    unsigned long long* degcnt =
        (unsigned long long*)((char*)xwH + (((size_t)E * 4 + 255) & ~(size_t)255));

    hipMemsetAsync(degcnt, 0, (size_t)N * 8, stream);
    hipMemsetAsync(out, 0, (size_t)64 * DFEAT * 4, stream);
    hipMemsetAsync(pool_cnt, 0, 64 * 4, stream);

    int gE = (E + 255) / 256;
    int gN = (N + 255) / 256;
    int nblk = (N + 1023) / 1024;

    pass1_k<<<gE, 256, 0, stream>>>(dst, ew, degcnt, rank, E);
    scan_block<<<nblk, 256, 0, stream>>>(degcnt, dinv, row_ptr, blksum, N);
    scan_small<<<1, 64, 0, stream>>>(blksum, nblk);
    scan_finish<<<gN, 256, 0, stream>>>(row_ptr, blksum, N, E);
    fill2_k<<<gE, 256, 0, stream>>>(src, dst, ew, rank, row_ptr, dinv, csr, E);

    int gG = (N + 15) / 16;
    int gA = (N + 3) / 4;
    // layer 0: x -> xwH -> h (relu)
    gemm128<<<gG, 256, 0, stream>>>(x, W0, xwH, N);
    agg_k<<<gA, 256, 0, stream>>>((const __half2*)xwH, row_ptr, csr, dinv, b0, h, 1, N);
    // layer 1: h -> xwH -> h (relu)
    gemm128<<<gG, 256, 0, stream>>>(h, W1, xwH, N);
    agg_k<<<gA, 256, 0, stream>>>((const __half2*)xwH, row_ptr, csr, dinv, b1, h, 1, N);
    // layer 2: h -> xwH -> h (no relu)
    gemm128<<<gG, 256, 0, stream>>>(h, W2, xwH, N);
    agg_k<<<gA, 256, 0, stream>>>((const __half2*)xwH, row_ptr, csr, dinv, b2, h, 0, N);

    pool_k<<<(N + 63) / 64, 128, 0, stream>>>(h, batch, out, pool_cnt, N);
    div_k<<<32, 256, 0, stream>>>(out, pool_cnt);
}

// Round 4
// 464.870 us; speedup vs baseline: 1.8226x; 1.2016x over previous
//
#include <hip/hip_runtime.h>
#include <hip/hip_fp16.h>

// ---------------------------------------------------------------------------
// GCNEncoder: 3x GCNConv(128->128) + ReLU(2x) + global mean pool (64 graphs)
//   - packed 64-bit atomic per edge -> {count, deg} + edge rank; CSR fill
//     has no atomics. CSR entries int2{src, norm}.
//   - activations fp16 everywhere (gather + write traffic halved); fp32 accum.
//   - GEMM via v_mfma_f32_16x16x32_f16, W split hi/lo (fp32-accurate W,
//     systematic error eliminated; per-node fp16 noise pools away).
//   - W pre-swizzled into MFMA B-fragment order once; inner loop is
//     ds_read_b128 + MFMA only.
// ---------------------------------------------------------------------------

#define DFEAT 128

typedef _Float16 half8 __attribute__((ext_vector_type(8)));
typedef float floatx4 __attribute__((ext_vector_type(4)));

// Pass 1: packed atomic. high32 = edge count, low32 = sum(ew) in 2^-24 fixed pt.
__global__ void pass1_k(const int* __restrict__ dst, const float* __restrict__ ew,
                        unsigned long long* __restrict__ degcnt,
                        int* __restrict__ rank, int E) {
    int e = blockIdx.x * 256 + threadIdx.x;
    if (e < E) {
        int d = dst[e];
        unsigned int fx = (unsigned int)(ew[e] * 16777216.0f);  // 2^24
        unsigned long long inc = (1ULL << 32) | (unsigned long long)fx;
        unsigned long long old = atomicAdd(&degcnt[d], inc);
        rank[e] = (int)(old >> 32);
    }
}

// Fused: unpack degcnt -> dinv, and block-level exclusive scan of counts.
__global__ __launch_bounds__(256) void scan_block(const unsigned long long* __restrict__ degcnt,
                                                  float* __restrict__ dinv,
                                                  int* __restrict__ excl,
                                                  int* __restrict__ blksum, int n) {
    int tid = threadIdx.x;
    int base = blockIdx.x * 1024 + tid * 4;
    int v0 = 0, v1 = 0, v2 = 0, v3 = 0;
    #define UNPACK(K, VK)                                                        \
        if (base + K < n) {                                                      \
            unsigned long long p = degcnt[base + K];                             \
            float deg = (float)((p & 0xffffffffULL) * (1.0f / 16777216.0f)) + 1.0f; \
            dinv[base + K] = rsqrtf(deg);                                        \
            VK = (int)(p >> 32);                                                 \
        }
    UNPACK(0, v0) UNPACK(1, v1) UNPACK(2, v2) UNPACK(3, v3)
    #undef UNPACK
    int tsum = v0 + v1 + v2 + v3;
    int lane = tid & 63;
    int incl = tsum;
    #pragma unroll
    for (int off = 1; off < 64; off <<= 1) {
        int u = __shfl_up(incl, (unsigned)off, 64);
        if (lane >= off) incl += u;
    }
    __shared__ int wtot[4];
    int wave = tid >> 6;
    if (lane == 63) wtot[wave] = incl;
    __syncthreads();
    int woff = 0;
    for (int w = 0; w < wave; w++) woff += wtot[w];
    int texcl = woff + incl - tsum;
    if (base + 0 < n) excl[base + 0] = texcl;
    if (base + 1 < n) excl[base + 1] = texcl + v0;
    if (base + 2 < n) excl[base + 2] = texcl + v0 + v1;
    if (base + 3 < n) excl[base + 3] = texcl + v0 + v1 + v2;
    if (tid == 255) blksum[blockIdx.x] = woff + incl;
}

__global__ void scan_small(int* __restrict__ blksum, int nb) {
    int lane = threadIdx.x;
    int v = (lane < nb) ? blksum[lane] : 0;
    int incl = v;
    #pragma unroll
    for (int off = 1; off < 64; off <<= 1) {
        int u = __shfl_up(incl, (unsigned)off, 64);
        if (lane >= off) incl += u;
    }
    if (lane < nb) blksum[lane] = incl - v;
}

__global__ void scan_finish(int* __restrict__ row_ptr,
                            const int* __restrict__ blksum, int n, int E) {
    int i = blockIdx.x * 256 + threadIdx.x;
    if (i < n) row_ptr[i] += blksum[i >> 10];
    if (i == 0) row_ptr[n] = E;
}

// Pass 2: no atomics. pos = row_ptr[dst] + rank. One 8B scattered write.
__global__ void fill2_k(const int* __restrict__ src, const int* __restrict__ dst,
                        const float* __restrict__ ew, const int* __restrict__ rank,
                        const int* __restrict__ row_ptr, const float* __restrict__ dinv,
                        int2* __restrict__ csr, int E) {
    int e = blockIdx.x * 256 + threadIdx.x;
    if (e < E) {
        int d = dst[e], s = src[e];
        int pos = row_ptr[d] + rank[e];
        float nm = dinv[s] * ew[e] * dinv[d];
        csr[pos] = make_int2(s, __float_as_int(nm));
    }
}

// x (fp32) -> fp16
__global__ void xconv_k(const float* __restrict__ x, _Float16* __restrict__ xh, int total4) {
    int i = blockIdx.x * 256 + threadIdx.x;
    if (i < total4) {
        float4 v = ((const float4*)x)[i];
        _Float16 o[4] = {(_Float16)v.x, (_Float16)v.y, (_Float16)v.z, (_Float16)v.w};
        ((uint2*)xh)[i] = *(uint2*)o;
    }
}

// W[3] fp32 -> swizzled fp16 hi/lo in MFMA B-fragment order.
// frag layout: halves offset ((kk*8 + t)*64 + L)*8 + j where
//   k = kk*32 + (L>>4)*8 + j  (L>>4 = quad), n = t*16 + (L&15)
__global__ void wconv_k(const float* __restrict__ W0, const float* __restrict__ W1,
                        const float* __restrict__ W2, _Float16* __restrict__ Wsw) {
    int idx = blockIdx.x * 256 + threadIdx.x;
    if (idx >= 3 * 128 * 128) return;
    int w = idx >> 14;
    int r = idx & 16383;
    int k = r >> 7, nn = r & 127;
    const float* W = (w == 0) ? W0 : (w == 1) ? W1 : W2;
    float v = W[k * 128 + nn];
    _Float16 hi = (_Float16)v;
    _Float16 lo = (_Float16)((v - (float)hi) * 1024.0f);
    int kk = k >> 5, quad = (k >> 3) & 3, j = k & 7;
    int t = nn >> 4, L = quad * 16 + (nn & 15);
    int off = ((kk * 8 + t) * 64 + L) * 8 + j;
    Wsw[(size_t)(w * 2 + 0) * 16384 + off] = hi;
    Wsw[(size_t)(w * 2 + 1) * 16384 + off] = lo;
}

// C[n,128] = A[n,128] @ W; MFMA 16x16x32 f16, split-precision W.
// Block: 256 threads = 4 waves; 64 rows/block; N=128 -> 8 tiles/wave.
__global__ __launch_bounds__(256) void gemm_mfma(const _Float16* __restrict__ A,
                                                 const _Float16* __restrict__ Wsw,
                                                 _Float16* __restrict__ C, int n) {
    __shared__ _Float16 Bl[2 * 16384];  // 64 KB: hi then lo
    {
        const uint4* s = (const uint4*)Wsw;
        uint4* d = (uint4*)Bl;
        for (int i = threadIdx.x; i < 4096; i += 256) d[i] = s[i];
    }
    int wave = threadIdx.x >> 6, lane = threadIdx.x & 63;
    int quad = lane >> 4, mcol = lane & 15;
    int row0 = blockIdx.x * 64 + wave * 16 + mcol;
    half8 af[4] = {};
    if (row0 < n) {
        const half8* Arow = (const half8*)(A + (size_t)row0 * DFEAT);
        af[0] = Arow[0 + quad];
        af[1] = Arow[4 + quad];
        af[2] = Arow[8 + quad];
        af[3] = Arow[12 + quad];
    }
    __syncthreads();
    floatx4 acch[8] = {};
    floatx4 accl[8] = {};
    const half8* Bh = (const half8*)Bl;
    const half8* Blo = (const half8*)(Bl + 16384);
    #pragma unroll
    for (int kk = 0; kk < 4; kk++) {
        #pragma unroll
        for (int t = 0; t < 8; t++) {
            half8 bh = Bh[(kk * 8 + t) * 64 + lane];
            acch[t] = __builtin_amdgcn_mfma_f32_16x16x32_f16(af[kk], bh, acch[t], 0, 0, 0);
            half8 bl = Blo[(kk * 8 + t) * 64 + lane];
            accl[t] = __builtin_amdgcn_mfma_f32_16x16x32_f16(af[kk], bl, accl[t], 0, 0, 0);
        }
    }
    int orow_base = blockIdx.x * 64 + wave * 16 + quad * 4;
    #pragma unroll
    for (int t = 0; t < 8; t++) {
        #pragma unroll
        for (int r = 0; r < 4; r++) {
            int orow = orow_base + r;
            if (orow < n) {
                float v = acch[t][r] + accl[t][r] * (1.0f / 1024.0f);
                C[(size_t)orow * DFEAT + t * 16 + mcol] = (_Float16)v;
            }
        }
    }
}

// 4 nodes per 256-thread block (one wave each); lane holds 2 fp16 features.
__global__ __launch_bounds__(256) void agg_k(const __half2* __restrict__ xw2,
                                             const int* __restrict__ row_ptr,
                                             const int2* __restrict__ csr,
                                             const float* __restrict__ dinv,
                                             const float* __restrict__ bias,
                                             __half2* __restrict__ out, int relu, int n) {
    int node = blockIdx.x * 4 + (threadIdx.x >> 6);
    if (node >= n) return;
    int lane = threadIdx.x & 63;
    float di = dinv[node];
    float2 selfv = __half22float2(xw2[(size_t)node * 64 + lane]);
    float sc = di * di;
    float ax = sc * selfv.x, ay = sc * selfv.y;
    int e = row_ptr[node], end = row_ptr[node + 1];
    for (; e + 8 <= end; e += 8) {
        int2 c0 = csr[e + 0], c1 = csr[e + 1], c2 = csr[e + 2], c3 = csr[e + 3];
        int2 c4 = csr[e + 4], c5 = csr[e + 5], c6 = csr[e + 6], c7 = csr[e + 7];
        float2 v0 = __half22float2(xw2[(size_t)c0.x * 64 + lane]);
        float2 v1 = __half22float2(xw2[(size_t)c1.x * 64 + lane]);
        float2 v2 = __half22float2(xw2[(size_t)c2.x * 64 + lane]);
        float2 v3 = __half22float2(xw2[(size_t)c3.x * 64 + lane]);
        float2 v4 = __half22float2(xw2[(size_t)c4.x * 64 + lane]);
        float2 v5 = __half22float2(xw2[(size_t)c5.x * 64 + lane]);
        float2 v6 = __half22float2(xw2[(size_t)c6.x * 64 + lane]);
        float2 v7 = __half22float2(xw2[(size_t)c7.x * 64 + lane]);
        float w0 = __int_as_float(c0.y), w1 = __int_as_float(c1.y);
        float w2 = __int_as_float(c2.y), w3 = __int_as_float(c3.y);
        float w4 = __int_as_float(c4.y), w5 = __int_as_float(c5.y);
        float w6 = __int_as_float(c6.y), w7 = __int_as_float(c7.y);
        ax = fmaf(w0, v0.x, ax); ay = fmaf(w0, v0.y, ay);
        ax = fmaf(w1, v1.x, ax); ay = fmaf(w1, v1.y, ay);
        ax = fmaf(w2, v2.x, ax); ay = fmaf(w2, v2.y, ay);
        ax = fmaf(w3, v3.x, ax); ay = fmaf(w3, v3.y, ay);
        ax = fmaf(w4, v4.x, ax); ay = fmaf(w4, v4.y, ay);
        ax = fmaf(w5, v5.x, ax); ay = fmaf(w5, v5.y, ay);
        ax = fmaf(w6, v6.x, ax); ay = fmaf(w6, v6.y, ay);
        ax = fmaf(w7, v7.x, ax); ay = fmaf(w7, v7.y, ay);
    }
    for (; e < end; e++) {
        int2 c = csr[e];
        float w = __int_as_float(c.y);
        float2 v = __half22float2(xw2[(size_t)c.x * 64 + lane]);
        ax = fmaf(w, v.x, ax); ay = fmaf(w, v.y, ay);
    }
    float2 bv = ((const float2*)bias)[lane];
    ax += bv.x; ay += bv.y;
    if (relu) { ax = fmaxf(ax, 0.f); ay = fmaxf(ay, 0.f); }
    out[(size_t)node * 64 + lane] = __floats2half2_rn(ax, ay);
}

// batch is sorted: chunk of 64 nodes per block, 128 threads (one per feature).
__global__ __launch_bounds__(128) void pool_k(const __half* __restrict__ h,
                                              const int* __restrict__ batch,
                                              float* __restrict__ out,
                                              float* __restrict__ pool_cnt, int n) {
    int j = threadIdx.x;
    int start = blockIdx.x * 64;
    if (start >= n) return;
    int end = start + 64; if (end > n) end = n;
    int g = batch[start];
    float acc = 0.f;
    float ccnt = 0.f;
    for (int i = start; i < end; i++) {
        int bi = batch[i];
        if (bi != g) {
            atomicAdd(&out[g * DFEAT + j], acc);
            if (j == 0) atomicAdd(&pool_cnt[g], ccnt);
            acc = 0.f; ccnt = 0.f; g = bi;
        }
        acc += __half2float(h[(size_t)i * DFEAT + j]);
        ccnt += 1.f;
    }
    atomicAdd(&out[g * DFEAT + j], acc);
    if (j == 0) atomicAdd(&pool_cnt[g], ccnt);
}

__global__ void div_k(float* __restrict__ out, const float* __restrict__ cnt) {
    int idx = blockIdx.x * 256 + threadIdx.x;
    if (idx < 64 * DFEAT) {
        float c = cnt[idx >> 7];
        out[idx] = out[idx] / fmaxf(c, 1.0f);
    }
}

extern "C" void kernel_launch(void* const* d_in, const int* in_sizes, int n_in,
                              void* d_out, int out_size, void* d_ws, size_t ws_size,
                              hipStream_t stream) {
    const float* x    = (const float*)d_in[0];
    const int*  eidx  = (const int*)d_in[1];
    const float* ew   = (const float*)d_in[2];
    const int*  batch = (const int*)d_in[3];
    const float* W0 = (const float*)d_in[4];
    const float* b0 = (const float*)d_in[5];
    const float* W1 = (const float*)d_in[6];
    const float* b1 = (const float*)d_in[7];
    const float* W2 = (const float*)d_in[8];
    const float* b2 = (const float*)d_in[9];
    float* out = (float*)d_out;

    const int N = in_sizes[0] / DFEAT;   // 50000
    const int E = in_sizes[2];           // 1600000
    const int* src = eidx;
    const int* dst = eidx + E;

    size_t off = 0;
    auto walloc = [&](size_t bytes) -> void* {
        void* p = (char*)d_ws + off;
        off += (bytes + 255) & ~(size_t)255;
        return p;
    };
    float*   dinv    = (float*)  walloc((size_t)N * 4);
    int*     row_ptr = (int*)    walloc((size_t)(N + 1) * 4);
    int*     blksum  = (int*)    walloc(256 * 4);
    int2*    csr     = (int2*)   walloc((size_t)E * 8);
    _Float16* xh     = (_Float16*)walloc((size_t)N * DFEAT * 2);  // also rank+degcnt early
    _Float16* xwH    = (_Float16*)walloc((size_t)N * DFEAT * 2);
    _Float16* hH     = (_Float16*)walloc((size_t)N * DFEAT * 2);
    _Float16* Wsw    = (_Float16*)walloc((size_t)6 * 16384 * 2);  // 3 W x {hi,lo} x 32KB
    float*   pool_cnt= (float*)  walloc(64 * 4);
    // rank + degcnt alias into xh region (dead before xconv_k writes xh)
    int* rank = (int*)xh;
    unsigned long long* degcnt =
        (unsigned long long*)((char*)xh + (((size_t)E * 4 + 255) & ~(size_t)255));

    hipMemsetAsync(degcnt, 0, (size_t)N * 8, stream);
    hipMemsetAsync(out, 0, (size_t)64 * DFEAT * 4, stream);
    hipMemsetAsync(pool_cnt, 0, 64 * 4, stream);

    int gE = (E + 255) / 256;
    int gN = (N + 255) / 256;
    int nblk = (N + 1023) / 1024;

    pass1_k<<<gE, 256, 0, stream>>>(dst, ew, degcnt, rank, E);
    scan_block<<<nblk, 256, 0, stream>>>(degcnt, dinv, row_ptr, blksum, N);
    scan_small<<<1, 64, 0, stream>>>(blksum, nblk);
    scan_finish<<<gN, 256, 0, stream>>>(row_ptr, blksum, N, E);
    fill2_k<<<gE, 256, 0, stream>>>(src, dst, ew, rank, row_ptr, dinv, csr, E);
    // rank/degcnt now dead; xh region reusable
    xconv_k<<<(N * DFEAT / 4 + 255) / 256, 256, 0, stream>>>(x, xh, N * DFEAT / 4);
    wconv_k<<<(3 * 16384 + 255) / 256, 256, 0, stream>>>(W0, W1, W2, Wsw);

    int gG = (N + 63) / 64;
    int gA = (N + 3) / 4;
    // layer 0
    gemm_mfma<<<gG, 256, 0, stream>>>(xh, Wsw + (size_t)0 * 32768, xwH, N);
    agg_k<<<gA, 256, 0, stream>>>((const __half2*)xwH, row_ptr, csr, dinv, b0,
                                  (__half2*)hH, 1, N);
    // layer 1
    gemm_mfma<<<gG, 256, 0, stream>>>(hH, Wsw + (size_t)1 * 32768, xwH, N);
    agg_k<<<gA, 256, 0, stream>>>((const __half2*)xwH, row_ptr, csr, dinv, b1,
                                  (__half2*)hH, 1, N);
    // layer 2
    gemm_mfma<<<gG, 256, 0, stream>>>(hH, Wsw + (size_t)2 * 32768, xwH, N);
    agg_k<<<gA, 256, 0, stream>>>((const __half2*)xwH, row_ptr, csr, dinv, b2,
                                  (__half2*)hH, 0, N);

    pool_k<<<(N + 63) / 64, 128, 0, stream>>>((const __half*)hH, batch, out, pool_cnt, N);
    div_k<<<32, 256, 0, stream>>>(out, pool_cnt);
}

// Round 5
// 399.792 us; speedup vs baseline: 2.1193x; 1.1628x over previous
//
#include <hip/hip_runtime.h>
#include <hip/hip_fp16.h>

// ---------------------------------------------------------------------------
// GCNEncoder: 3x GCNConv(128->128) + ReLU(2x) + global mean pool (64 graphs)
//   - CSR build with ZERO global atomics: two-level counting sort
//     (block histograms over 196 coarse buckets -> scan -> LDS-sorted
//      coalesced scatter -> per-bucket CSR build in one 65KB L2 window).
//   - activations fp16 everywhere; fp32 accumulation.
//   - GEMM via v_mfma_f32_16x16x32_f16, W split hi/lo (fp32-accurate W).
//   - layer-0 GEMM reads fp32 x directly (no separate convert pass).
// ---------------------------------------------------------------------------

#define DFEAT 128
#define BLK_E 4096   // edges per sort block

typedef _Float16 half8 __attribute__((ext_vector_type(8)));
typedef float floatx4 __attribute__((ext_vector_type(4)));

__device__ __forceinline__ int wave_incl_scan(int v) {
    int incl = v;
    #pragma unroll
    for (int off = 1; off < 64; off <<= 1) {
        int u = __shfl_up(incl, (unsigned)off, 64);
        if ((int)(threadIdx.x & 63) >= off) incl += u;
    }
    return incl;
}

// K1: per-block histogram over coarse buckets (dst >> 8), bin-major output.
__global__ __launch_bounds__(256) void hist_k(const int* __restrict__ dst,
                                              int* __restrict__ hist,
                                              int E, int nblk, int nbuck) {
    __shared__ int h[256];
    int tid = threadIdx.x, b = blockIdx.x;
    h[tid] = 0;
    __syncthreads();
    int base = b * BLK_E;
    int nE = min(BLK_E, E - base);
    for (int i = tid; i < nE; i += 256) atomicAdd(&h[dst[base + i] >> 8], 1);
    __syncthreads();
    if (tid < nbuck) hist[tid * nblk + b] = h[tid];
}

// Generic exclusive scan, 1024 elems/block, in-place. Values read for
// i < n_val (else 0); exclusive prefix written for i < n_scan.
__global__ __launch_bounds__(256) void scanb_k(int* __restrict__ arr,
                                               int* __restrict__ blksum,
                                               int n_val, int n_scan) {
    int tid = threadIdx.x;
    int base = blockIdx.x * 1024 + tid * 4;
    int v0 = (base + 0 < n_val) ? arr[base + 0] : 0;
    int v1 = (base + 1 < n_val) ? arr[base + 1] : 0;
    int v2 = (base + 2 < n_val) ? arr[base + 2] : 0;
    int v3 = (base + 3 < n_val) ? arr[base + 3] : 0;
    int tsum = v0 + v1 + v2 + v3;
    int incl = wave_incl_scan(tsum);
    __shared__ int wtot[4];
    if ((tid & 63) == 63) wtot[tid >> 6] = incl;
    __syncthreads();
    int woff = 0;
    for (int w = 0; w < (tid >> 6); w++) woff += wtot[w];
    int texcl = woff + incl - tsum;
    if (base + 0 < n_scan) arr[base + 0] = texcl;
    if (base + 1 < n_scan) arr[base + 1] = texcl + v0;
    if (base + 2 < n_scan) arr[base + 2] = texcl + v0 + v1;
    if (base + 3 < n_scan) arr[base + 3] = texcl + v0 + v1 + v2;
    if (tid == 255) blksum[blockIdx.x] = woff + incl;
}

__global__ __launch_bounds__(256) void scan_small256(int* __restrict__ blksum, int nb) {
    int tid = threadIdx.x;
    int v = (tid < nb) ? blksum[tid] : 0;
    int incl = wave_incl_scan(v);
    __shared__ int wtot[4];
    if ((tid & 63) == 63) wtot[tid >> 6] = incl;
    __syncthreads();
    int woff = 0;
    for (int w = 0; w < (tid >> 6); w++) woff += wtot[w];
    if (tid < nb) blksum[tid] = woff + incl - v;
}

__global__ void scanf_k(int* __restrict__ arr, const int* __restrict__ blksum, int n_scan) {
    int i = blockIdx.x * 256 + threadIdx.x;
    if (i < n_scan) arr[i] += blksum[i >> 10];
}

// K3: scatter edges into bucket-grouped array, coalesced via LDS sort.
// rec = {src | dstlow<<16, ew_bits}. Requires N <= 65536.
__global__ __launch_bounds__(256) void scat_k(const int* __restrict__ src,
                                              const int* __restrict__ dst,
                                              const float* __restrict__ ew,
                                              const int* __restrict__ offs,
                                              uint2* __restrict__ rec,
                                              int E, int nblk, int nbuck) {
    __shared__ int lcur[256];
    __shared__ int gbase[256];
    __shared__ uint2 srec[BLK_E];
    __shared__ int gpos[BLK_E];
    int tid = threadIdx.x, b = blockIdx.x;
    lcur[tid] = 0;
    __syncthreads();
    int base = b * BLK_E;
    int nE = min(BLK_E, E - base);
    for (int i = tid; i < nE; i += 256) atomicAdd(&lcur[dst[base + i] >> 8], 1);
    __syncthreads();
    int v = lcur[tid];
    int incl = wave_incl_scan(v);
    __shared__ int wtot[4];
    if ((tid & 63) == 63) wtot[tid >> 6] = incl;
    __syncthreads();
    int woff = 0;
    for (int w = 0; w < (tid >> 6); w++) woff += wtot[w];
    int excl = woff + incl - v;
    __syncthreads();
    lcur[tid] = excl;
    gbase[tid] = (tid < nbuck) ? (offs[tid * nblk + b] - excl) : 0;
    __syncthreads();
    for (int i = tid; i < nE; i += 256) {
        int e = base + i;
        int d = dst[e];
        int bin = d >> 8;
        int slot = atomicAdd(&lcur[bin], 1);
        uint2 r;
        r.x = (unsigned)src[e] | ((unsigned)(d & 255) << 16);
        r.y = __float_as_uint(ew[e]);
        srec[slot] = r;
        gpos[slot] = gbase[bin] + slot;
    }
    __syncthreads();
    for (int i = tid; i < nE; i += 256) rec[gpos[i]] = srec[i];
}

// K4: one block per 256-node bucket. Per-node counts + fixed-point deg in
// LDS, scan -> row_ptr/dinv, then place CSR entries {src, ew*dinv[dst]}.
__global__ __launch_bounds__(1024) void bucket_k(const uint2* __restrict__ rec,
                                                 const int* __restrict__ offs,
                                                 float* __restrict__ dinv,
                                                 int* __restrict__ row_ptr,
                                                 uint2* __restrict__ csr,
                                                 int N, int nblk) {
    __shared__ int cnt[256];
    __shared__ unsigned degfx[256];
    __shared__ int excl_s[256];
    __shared__ int cur[256];
    __shared__ int wtot[4];
    int tid = threadIdx.x, bin = blockIdx.x;
    int start = offs[bin * nblk];
    int endp = offs[(bin + 1) * nblk];   // sentinel at offs[nbuck*nblk] = E
    if (tid < 256) { cnt[tid] = 0; degfx[tid] = 0; }
    __syncthreads();
    for (int i = start + tid; i < endp; i += 1024) {
        uint2 r = rec[i];
        int dl = (r.x >> 16) & 255;
        atomicAdd(&cnt[dl], 1);
        atomicAdd(&degfx[dl], (unsigned)(__uint_as_float(r.y) * 1048576.0f + 0.5f));
    }
    __syncthreads();
    int v = 0, incl = 0;
    if (tid < 256) { v = cnt[tid]; incl = wave_incl_scan(v); }
    if (tid < 256 && (tid & 63) == 63) wtot[tid >> 6] = incl;
    __syncthreads();
    if (tid < 256) {
        int woff = 0;
        for (int w = 0; w < (tid >> 6); w++) woff += wtot[w];
        int e = woff + incl - v;
        excl_s[tid] = e;
        cur[tid] = e;
        int node = bin * 256 + tid;
        if (node < N) {
            row_ptr[node] = start + e;
            float deg = (float)degfx[tid] * (1.0f / 1048576.0f) + 1.0f;
            float di = rsqrtf(deg);
            dinv[node] = di;
            degfx[tid] = __float_as_uint(di);   // reuse as dinv stash
        }
    }
    __syncthreads();
    for (int i = start + tid; i < endp; i += 1024) {
        uint2 r = rec[i];
        int dl = (r.x >> 16) & 255;
        int p = start + atomicAdd(&cur[dl], 1);
        float di_d = __uint_as_float(degfx[dl]);
        uint2 c;
        c.x = r.x & 0xffff;
        c.y = __float_as_uint(__uint_as_float(r.y) * di_d);
        csr[p] = c;
    }
}

// K5: scale by dinv[src]; also writes row_ptr[N].
__global__ void normfix_k(uint2* __restrict__ csr, const float* __restrict__ dinv,
                          int* __restrict__ row_ptr, int E, int N) {
    int e = blockIdx.x * 256 + threadIdx.x;
    if (e < E) {
        uint2 c = csr[e];
        c.y = __float_as_uint(__uint_as_float(c.y) * dinv[c.x]);
        csr[e] = c;
    }
    if (e == 0) row_ptr[N] = E;
}

// W[3] fp32 -> swizzled fp16 hi/lo in MFMA B-fragment order.
__global__ void wconv_k(const float* __restrict__ W0, const float* __restrict__ W1,
                        const float* __restrict__ W2, _Float16* __restrict__ Wsw) {
    int idx = blockIdx.x * 256 + threadIdx.x;
    if (idx >= 3 * 128 * 128) return;
    int w = idx >> 14;
    int r = idx & 16383;
    int k = r >> 7, nn = r & 127;
    const float* W = (w == 0) ? W0 : (w == 1) ? W1 : W2;
    float v = W[k * 128 + nn];
    _Float16 hi = (_Float16)v;
    _Float16 lo = (_Float16)((v - (float)hi) * 1024.0f);
    int kk = k >> 5, quad = (k >> 3) & 3, j = k & 7;
    int t = nn >> 4, L = quad * 16 + (nn & 15);
    int off = ((kk * 8 + t) * 64 + L) * 8 + j;
    Wsw[(size_t)(w * 2 + 0) * 16384 + off] = hi;
    Wsw[(size_t)(w * 2 + 1) * 16384 + off] = lo;
}

// MFMA GEMM core (A fp16). Block: 4 waves, 64 rows; 8 col-tiles per wave.
__global__ __launch_bounds__(256) void gemm_mfma(const _Float16* __restrict__ A,
                                                 const _Float16* __restrict__ Wsw,
                                                 _Float16* __restrict__ C, int n) {
    __shared__ _Float16 Bl[2 * 16384];
    {
        const uint4* s = (const uint4*)Wsw;
        uint4* d = (uint4*)Bl;
        for (int i = threadIdx.x; i < 4096; i += 256) d[i] = s[i];
    }
    int wave = threadIdx.x >> 6, lane = threadIdx.x & 63;
    int quad = lane >> 4, mcol = lane & 15;
    int row0 = blockIdx.x * 64 + wave * 16 + mcol;
    half8 af[4] = {};
    if (row0 < n) {
        const half8* Arow = (const half8*)(A + (size_t)row0 * DFEAT);
        af[0] = Arow[0 + quad];
        af[1] = Arow[4 + quad];
        af[2] = Arow[8 + quad];
        af[3] = Arow[12 + quad];
    }
    __syncthreads();
    floatx4 acch[8] = {};
    floatx4 accl[8] = {};
    const half8* Bh = (const half8*)Bl;
    const half8* Blo = (const half8*)(Bl + 16384);
    #pragma unroll
    for (int kk = 0; kk < 4; kk++) {
        #pragma unroll
        for (int t = 0; t < 8; t++) {
            half8 bh = Bh[(kk * 8 + t) * 64 + lane];
            acch[t] = __builtin_amdgcn_mfma_f32_16x16x32_f16(af[kk], bh, acch[t], 0, 0, 0);
            half8 bl = Blo[(kk * 8 + t) * 64 + lane];
            accl[t] = __builtin_amdgcn_mfma_f32_16x16x32_f16(af[kk], bl, accl[t], 0, 0, 0);
        }
    }
    int orow_base = blockIdx.x * 64 + wave * 16 + quad * 4;
    #pragma unroll
    for (int t = 0; t < 8; t++) {
        #pragma unroll
        for (int r = 0; r < 4; r++) {
            int orow = orow_base + r;
            if (orow < n) {
                float v = acch[t][r] + accl[t][r] * (1.0f / 1024.0f);
                C[(size_t)orow * DFEAT + t * 16 + mcol] = (_Float16)v;
            }
        }
    }
}

// Same, but reads fp32 A (layer 0: x directly, no convert pass).
__global__ __launch_bounds__(256) void gemm_mfma_f32(const float* __restrict__ A,
                                                     const _Float16* __restrict__ Wsw,
                                                     _Float16* __restrict__ C, int n) {
    __shared__ _Float16 Bl[2 * 16384];
    {
        const uint4* s = (const uint4*)Wsw;
        uint4* d = (uint4*)Bl;
        for (int i = threadIdx.x; i < 4096; i += 256) d[i] = s[i];
    }
    int wave = threadIdx.x >> 6, lane = threadIdx.x & 63;
    int quad = lane >> 4, mcol = lane & 15;
    int row0 = blockIdx.x * 64 + wave * 16 + mcol;
    half8 af[4] = {};
    if (row0 < n) {
        const float4* Arow = (const float4*)(A + (size_t)row0 * DFEAT);
        #pragma unroll
        for (int kk = 0; kk < 4; kk++) {
            float4 f0 = Arow[kk * 8 + quad * 2];
            float4 f1 = Arow[kk * 8 + quad * 2 + 1];
            half8 a;
            a[0] = (_Float16)f0.x; a[1] = (_Float16)f0.y;
            a[2] = (_Float16)f0.z; a[3] = (_Float16)f0.w;
            a[4] = (_Float16)f1.x; a[5] = (_Float16)f1.y;
            a[6] = (_Float16)f1.z; a[7] = (_Float16)f1.w;
            af[kk] = a;
        }
    }
    __syncthreads();
    floatx4 acch[8] = {};
    floatx4 accl[8] = {};
    const half8* Bh = (const half8*)Bl;
    const half8* Blo = (const half8*)(Bl + 16384);
    #pragma unroll
    for (int kk = 0; kk < 4; kk++) {
        #pragma unroll
        for (int t = 0; t < 8; t++) {
            half8 bh = Bh[(kk * 8 + t) * 64 + lane];
            acch[t] = __builtin_amdgcn_mfma_f32_16x16x32_f16(af[kk], bh, acch[t], 0, 0, 0);
            half8 bl = Blo[(kk * 8 + t) * 64 + lane];
            accl[t] = __builtin_amdgcn_mfma_f32_16x16x32_f16(af[kk], bl, accl[t], 0, 0, 0);
        }
    }
    int orow_base = blockIdx.x * 64 + wave * 16 + quad * 4;
    #pragma unroll
    for (int t = 0; t < 8; t++) {
        #pragma unroll
        for (int r = 0; r < 4; r++) {
            int orow = orow_base + r;
            if (orow < n) {
                float v = acch[t][r] + accl[t][r] * (1.0f / 1024.0f);
                C[(size_t)orow * DFEAT + t * 16 + mcol] = (_Float16)v;
            }
        }
    }
}

// 4 nodes per 256-thread block (one wave each); lane holds 2 fp16 features.
__global__ __launch_bounds__(256) void agg_k(const __half2* __restrict__ xw2,
                                             const int* __restrict__ row_ptr,
                                             const int2* __restrict__ csr,
                                             const float* __restrict__ dinv,
                                             const float* __restrict__ bias,
                                             __half2* __restrict__ out, int relu, int n) {
    int node = blockIdx.x * 4 + (threadIdx.x >> 6);
    if (node >= n) return;
    int lane = threadIdx.x & 63;
    float di = dinv[node];
    float2 selfv = __half22float2(xw2[(size_t)node * 64 + lane]);
    float sc = di * di;
    float ax = sc * selfv.x, ay = sc * selfv.y;
    int e = row_ptr[node], end = row_ptr[node + 1];
    for (; e + 8 <= end; e += 8) {
        int2 c0 = csr[e + 0], c1 = csr[e + 1], c2 = csr[e + 2], c3 = csr[e + 3];
        int2 c4 = csr[e + 4], c5 = csr[e + 5], c6 = csr[e + 6], c7 = csr[e + 7];
        float2 v0 = __half22float2(xw2[(size_t)c0.x * 64 + lane]);
        float2 v1 = __half22float2(xw2[(size_t)c1.x * 64 + lane]);
        float2 v2 = __half22float2(xw2[(size_t)c2.x * 64 + lane]);
        float2 v3 = __half22float2(xw2[(size_t)c3.x * 64 + lane]);
        float2 v4 = __half22float2(xw2[(size_t)c4.x * 64 + lane]);
        float2 v5 = __half22float2(xw2[(size_t)c5.x * 64 + lane]);
        float2 v6 = __half22float2(xw2[(size_t)c6.x * 64 + lane]);
        float2 v7 = __half22float2(xw2[(size_t)c7.x * 64 + lane]);
        float w0 = __int_as_float(c0.y), w1 = __int_as_float(c1.y);
        float w2 = __int_as_float(c2.y), w3 = __int_as_float(c3.y);
        float w4 = __int_as_float(c4.y), w5 = __int_as_float(c5.y);
        float w6 = __int_as_float(c6.y), w7 = __int_as_float(c7.y);
        ax = fmaf(w0, v0.x, ax); ay = fmaf(w0, v0.y, ay);
        ax = fmaf(w1, v1.x, ax); ay = fmaf(w1, v1.y, ay);
        ax = fmaf(w2, v2.x, ax); ay = fmaf(w2, v2.y, ay);
        ax = fmaf(w3, v3.x, ax); ay = fmaf(w3, v3.y, ay);
        ax = fmaf(w4, v4.x, ax); ay = fmaf(w4, v4.y, ay);
        ax = fmaf(w5, v5.x, ax); ay = fmaf(w5, v5.y, ay);
        ax = fmaf(w6, v6.x, ax); ay = fmaf(w6, v6.y, ay);
        ax = fmaf(w7, v7.x, ax); ay = fmaf(w7, v7.y, ay);
    }
    for (; e < end; e++) {
        int2 c = csr[e];
        float w = __int_as_float(c.y);
        float2 v = __half22float2(xw2[(size_t)c.x * 64 + lane]);
        ax = fmaf(w, v.x, ax); ay = fmaf(w, v.y, ay);
    }
    float2 bv = ((const float2*)bias)[lane];
    ax += bv.x; ay += bv.y;
    if (relu) { ax = fmaxf(ax, 0.f); ay = fmaxf(ay, 0.f); }
    out[(size_t)node * 64 + lane] = __floats2half2_rn(ax, ay);
}

// batch is sorted: chunk of 64 nodes per block, 128 threads (one per feature).
__global__ __launch_bounds__(128) void pool_k(const __half* __restrict__ h,
                                              const int* __restrict__ batch,
                                              float* __restrict__ out,
                                              float* __restrict__ pool_cnt, int n) {
    int j = threadIdx.x;
    int start = blockIdx.x * 64;
    if (start >= n) return;
    int end = start + 64; if (end > n) end = n;
    int g = batch[start];
    float acc = 0.f;
    float ccnt = 0.f;
    for (int i = start; i < end; i++) {
        int bi = batch[i];
        if (bi != g) {
            atomicAdd(&out[g * DFEAT + j], acc);
            if (j == 0) atomicAdd(&pool_cnt[g], ccnt);
            acc = 0.f; ccnt = 0.f; g = bi;
        }
        acc += __half2float(h[(size_t)i * DFEAT + j]);
        ccnt += 1.f;
    }
    atomicAdd(&out[g * DFEAT + j], acc);
    if (j == 0) atomicAdd(&pool_cnt[g], ccnt);
}

__global__ void div_k(float* __restrict__ out, const float* __restrict__ cnt) {
    int idx = blockIdx.x * 256 + threadIdx.x;
    if (idx < 64 * DFEAT) {
        float c = cnt[idx >> 7];
        out[idx] = out[idx] / fmaxf(c, 1.0f);
    }
}

extern "C" void kernel_launch(void* const* d_in, const int* in_sizes, int n_in,
                              void* d_out, int out_size, void* d_ws, size_t ws_size,
                              hipStream_t stream) {
    const float* x    = (const float*)d_in[0];
    const int*  eidx  = (const int*)d_in[1];
    const float* ew   = (const float*)d_in[2];
    const int*  batch = (const int*)d_in[3];
    const float* W0 = (const float*)d_in[4];
    const float* b0 = (const float*)d_in[5];
    const float* W1 = (const float*)d_in[6];
    const float* b1 = (const float*)d_in[7];
    const float* W2 = (const float*)d_in[8];
    const float* b2 = (const float*)d_in[9];
    float* out = (float*)d_out;

    const int N = in_sizes[0] / DFEAT;   // 50000 (must be <= 65536)
    const int E = in_sizes[2];           // 1600000
    const int* src = eidx;
    const int* dst = eidx + E;

    const int nbuck = (N + 255) / 256;           // 196
    const int nblk  = (E + BLK_E - 1) / BLK_E;   // 391
    const int total = nbuck * nblk;
    const int n_scan = total + 1;                // sentinel -> E

    size_t off = 0;
    auto walloc = [&](size_t bytes) -> void* {
        void* p = (char*)d_ws + off;
        off += (bytes + 255) & ~(size_t)255;
        return p;
    };
    float*   dinv    = (float*)  walloc((size_t)N * 4);
    int*     row_ptr = (int*)    walloc((size_t)(N + 1) * 4);
    int*     offs    = (int*)    walloc((size_t)n_scan * 4);
    int*     blksum  = (int*)    walloc(256 * 4);
    uint2*   rec     = (uint2*)  walloc((size_t)E * 8);
    uint2*   csr     = (uint2*)  walloc((size_t)E * 8);
    _Float16* xwH    = (_Float16*)walloc((size_t)N * DFEAT * 2);
    _Float16* hH     = (_Float16*)walloc((size_t)N * DFEAT * 2);
    _Float16* Wsw    = (_Float16*)walloc((size_t)6 * 16384 * 2);
    float*   pool_cnt= (float*)  walloc(64 * 4);

    hipMemsetAsync(out, 0, (size_t)64 * DFEAT * 4, stream);
    hipMemsetAsync(pool_cnt, 0, 64 * 4, stream);

    // ---- CSR build (no global atomics) ----
    hist_k<<<nblk, 256, 0, stream>>>(dst, offs, E, nblk, nbuck);
    int nsb = (n_scan + 1023) / 1024;
    scanb_k<<<nsb, 256, 0, stream>>>(offs, blksum, total, n_scan);
    scan_small256<<<1, 256, 0, stream>>>(blksum, nsb);
    scanf_k<<<(n_scan + 255) / 256, 256, 0, stream>>>(offs, blksum, n_scan);
    scat_k<<<nblk, 256, 0, stream>>>(src, dst, ew, offs, rec, E, nblk, nbuck);
    bucket_k<<<nbuck, 1024, 0, stream>>>(rec, offs, dinv, row_ptr, csr, N, nblk);
    normfix_k<<<(E + 255) / 256, 256, 0, stream>>>(csr, dinv, row_ptr, E, N);

    wconv_k<<<(3 * 16384 + 255) / 256, 256, 0, stream>>>(W0, W1, W2, Wsw);

    int gG = (N + 63) / 64;
    int gA = (N + 3) / 4;
    // layer 0 (reads fp32 x directly)
    gemm_mfma_f32<<<gG, 256, 0, stream>>>(x, Wsw + (size_t)0 * 32768, xwH, N);
    agg_k<<<gA, 256, 0, stream>>>((const __half2*)xwH, row_ptr, (const int2*)csr,
                                  dinv, b0, (__half2*)hH, 1, N);
    // layer 1
    gemm_mfma<<<gG, 256, 0, stream>>>(hH, Wsw + (size_t)1 * 32768, xwH, N);
    agg_k<<<gA, 256, 0, stream>>>((const __half2*)xwH, row_ptr, (const int2*)csr,
                                  dinv, b1, (__half2*)hH, 1, N);
    // layer 2
    gemm_mfma<<<gG, 256, 0, stream>>>(hH, Wsw + (size_t)2 * 32768, xwH, N);
    agg_k<<<gA, 256, 0, stream>>>((const __half2*)xwH, row_ptr, (const int2*)csr,
                                  dinv, b2, (__half2*)hH, 0, N);

    pool_k<<<(N + 63) / 64, 128, 0, stream>>>((const __half*)hH, batch, out, pool_cnt, N);
    div_k<<<32, 256, 0, stream>>>(out, pool_cnt);
}

// Round 6
// 399.435 us; speedup vs baseline: 2.1212x; 1.0009x over previous
//
#include <hip/hip_runtime.h>
#include <hip/hip_fp16.h>

// ---------------------------------------------------------------------------
// GCNEncoder: 3x GCNConv(128->128) + ReLU(2x) + global mean pool (64 graphs)
//   - CSR build with ZERO global atomics: two-level counting sort.
//   - per-node edge lists ordered by src>>14 (4 partitions ~ L2-sized slices)
//     for temporal L2 locality in the gather.
//   - agg_k: 2 edges per wave (32-lane halves, 8B/lane gathers), shfl_xor
//     cross-half reduction. fp16 activations, fp32 accumulation.
//   - GEMM via v_mfma_f32_16x16x32_f16, W split hi/lo (fp32-accurate W).
// ---------------------------------------------------------------------------

#define DFEAT 128
#define BLK_E 4096   // edges per sort block

typedef _Float16 half8 __attribute__((ext_vector_type(8)));
typedef float floatx4 __attribute__((ext_vector_type(4)));

__device__ __forceinline__ int wave_incl_scan(int v) {
    int incl = v;
    #pragma unroll
    for (int off = 1; off < 64; off <<= 1) {
        int u = __shfl_up(incl, (unsigned)off, 64);
        if ((int)(threadIdx.x & 63) >= off) incl += u;
    }
    return incl;
}

// K1: per-block histogram over coarse buckets (dst >> 8), bin-major output.
__global__ __launch_bounds__(256) void hist_k(const int* __restrict__ dst,
                                              int* __restrict__ hist,
                                              int E, int nblk, int nbuck) {
    __shared__ int h[256];
    int tid = threadIdx.x, b = blockIdx.x;
    h[tid] = 0;
    __syncthreads();
    int base = b * BLK_E;
    int nE = min(BLK_E, E - base);
    for (int i = tid; i < nE; i += 256) atomicAdd(&h[dst[base + i] >> 8], 1);
    __syncthreads();
    if (tid < nbuck) hist[tid * nblk + b] = h[tid];
}

// Block-local exclusive scan, 1024 elems/block, in-place; blksum = totals.
// (Final value = arr[i] + blksum[i>>10]; consumers add blksum themselves.)
__global__ __launch_bounds__(256) void scanb_k(int* __restrict__ arr,
                                               int* __restrict__ blksum,
                                               int n_val, int n_scan) {
    int tid = threadIdx.x;
    int base = blockIdx.x * 1024 + tid * 4;
    int v0 = (base + 0 < n_val) ? arr[base + 0] : 0;
    int v1 = (base + 1 < n_val) ? arr[base + 1] : 0;
    int v2 = (base + 2 < n_val) ? arr[base + 2] : 0;
    int v3 = (base + 3 < n_val) ? arr[base + 3] : 0;
    int tsum = v0 + v1 + v2 + v3;
    int incl = wave_incl_scan(tsum);
    __shared__ int wtot[4];
    if ((tid & 63) == 63) wtot[tid >> 6] = incl;
    __syncthreads();
    int woff = 0;
    for (int w = 0; w < (tid >> 6); w++) woff += wtot[w];
    int texcl = woff + incl - tsum;
    if (base + 0 < n_scan) arr[base + 0] = texcl;
    if (base + 1 < n_scan) arr[base + 1] = texcl + v0;
    if (base + 2 < n_scan) arr[base + 2] = texcl + v0 + v1;
    if (base + 3 < n_scan) arr[base + 3] = texcl + v0 + v1 + v2;
    if (tid == 255) blksum[blockIdx.x] = woff + incl;
}

__global__ __launch_bounds__(256) void scan_small256(int* __restrict__ blksum, int nb) {
    int tid = threadIdx.x;
    int v = (tid < nb) ? blksum[tid] : 0;
    int incl = wave_incl_scan(v);
    __shared__ int wtot[4];
    if ((tid & 63) == 63) wtot[tid >> 6] = incl;
    __syncthreads();
    int woff = 0;
    for (int w = 0; w < (tid >> 6); w++) woff += wtot[w];
    if (tid < nb) blksum[tid] = woff + incl - v;
}

// K3: scatter edges into bucket-grouped array, coalesced via LDS sort.
// rec = {src | dstlow<<16, ew_bits}. Requires N <= 65536.
__global__ __launch_bounds__(256) void scat_k(const int* __restrict__ src,
                                              const int* __restrict__ dst,
                                              const float* __restrict__ ew,
                                              const int* __restrict__ offs,
                                              const int* __restrict__ blksum,
                                              uint2* __restrict__ rec,
                                              int E, int nblk, int nbuck) {
    __shared__ int lcur[256];
    __shared__ int gbase[256];
    __shared__ uint2 srec[BLK_E];
    __shared__ int gpos[BLK_E];
    int tid = threadIdx.x, b = blockIdx.x;
    lcur[tid] = 0;
    __syncthreads();
    int base = b * BLK_E;
    int nE = min(BLK_E, E - base);
    for (int i = tid; i < nE; i += 256) atomicAdd(&lcur[dst[base + i] >> 8], 1);
    __syncthreads();
    int v = lcur[tid];
    int incl = wave_incl_scan(v);
    __shared__ int wtot[4];
    if ((tid & 63) == 63) wtot[tid >> 6] = incl;
    __syncthreads();
    int woff = 0;
    for (int w = 0; w < (tid >> 6); w++) woff += wtot[w];
    int excl = woff + incl - v;
    __syncthreads();
    lcur[tid] = excl;
    int oidx = tid * nblk + b;
    gbase[tid] = (tid < nbuck) ? (offs[oidx] + blksum[oidx >> 10] - excl) : 0;
    __syncthreads();
    for (int i = tid; i < nE; i += 256) {
        int e = base + i;
        int d = dst[e];
        int bin = d >> 8;
        int slot = atomicAdd(&lcur[bin], 1);
        uint2 r;
        r.x = (unsigned)src[e] | ((unsigned)(d & 255) << 16);
        r.y = __float_as_uint(ew[e]);
        srec[slot] = r;
        gpos[slot] = gbase[bin] + slot;
    }
    __syncthreads();
    for (int i = tid; i < nE; i += 256) rec[gpos[i]] = srec[i];
}

// K4: one block per 256-node bucket. Per-(node, src>>14) counts + fixed-point
// deg in LDS, scan -> row_ptr/dinv, place CSR entries {src, ew*dinv[dst]}
// ordered by src partition within each node.
__global__ __launch_bounds__(1024) void bucket_k(const uint2* __restrict__ rec,
                                                 const int* __restrict__ offs,
                                                 const int* __restrict__ blksum,
                                                 float* __restrict__ dinv,
                                                 int* __restrict__ row_ptr,
                                                 uint2* __restrict__ csr,
                                                 int N, int nblk) {
    __shared__ int cnt[1024];       // key = dstlow*4 + src_part
    __shared__ unsigned degfx[256];
    __shared__ int cur[1024];
    __shared__ int wtot[16];
    int tid = threadIdx.x, bin = blockIdx.x;
    int idx0 = bin * nblk, idx1 = (bin + 1) * nblk;
    int start = offs[idx0] + blksum[idx0 >> 10];
    int endp  = offs[idx1] + blksum[idx1 >> 10];  // sentinel -> E for last bin
    cnt[tid] = 0;
    if (tid < 256) degfx[tid] = 0;
    __syncthreads();
    for (int i = start + tid; i < endp; i += 1024) {
        uint2 r = rec[i];
        int dl = (r.x >> 16) & 255;
        int part = (r.x & 0xffff) >> 14;
        atomicAdd(&cnt[dl * 4 + part], 1);
        atomicAdd(&degfx[dl], (unsigned)(__uint_as_float(r.y) * 1048576.0f + 0.5f));
    }
    __syncthreads();
    int v = cnt[tid];
    int incl = wave_incl_scan(v);
    if ((tid & 63) == 63) wtot[tid >> 6] = incl;
    __syncthreads();
    int woff = 0;
    for (int w = 0; w < (tid >> 6); w++) woff += wtot[w];
    cur[tid] = woff + incl - v;     // block-local exclusive prefix
    __syncthreads();
    if (tid < 256) {
        int node = bin * 256 + tid;
        if (node < N) {
            row_ptr[node] = start + cur[tid * 4];
            float deg = (float)degfx[tid] * (1.0f / 1048576.0f) + 1.0f;
            float di = rsqrtf(deg);
            dinv[node] = di;
            degfx[tid] = __float_as_uint(di);   // stash dinv
        }
    }
    __syncthreads();
    for (int i = start + tid; i < endp; i += 1024) {
        uint2 r = rec[i];
        int dl = (r.x >> 16) & 255;
        int s = r.x & 0xffff;
        int part = s >> 14;
        int p = start + atomicAdd(&cur[dl * 4 + part], 1);
        float di_d = __uint_as_float(degfx[dl]);
        uint2 c;
        c.x = (unsigned)s;
        c.y = __float_as_uint(__uint_as_float(r.y) * di_d);
        csr[p] = c;
    }
}

// K5: scale by dinv[src]; also writes row_ptr[N].
__global__ void normfix_k(uint2* __restrict__ csr, const float* __restrict__ dinv,
                          int* __restrict__ row_ptr, int E, int N) {
    int e = blockIdx.x * 256 + threadIdx.x;
    if (e < E) {
        uint2 c = csr[e];
        c.y = __float_as_uint(__uint_as_float(c.y) * dinv[c.x]);
        csr[e] = c;
    }
    if (e == 0) row_ptr[N] = E;
}

// W[3] fp32 -> swizzled fp16 hi/lo in MFMA B-fragment order.
__global__ void wconv_k(const float* __restrict__ W0, const float* __restrict__ W1,
                        const float* __restrict__ W2, _Float16* __restrict__ Wsw) {
    int idx = blockIdx.x * 256 + threadIdx.x;
    if (idx >= 3 * 128 * 128) return;
    int w = idx >> 14;
    int r = idx & 16383;
    int k = r >> 7, nn = r & 127;
    const float* W = (w == 0) ? W0 : (w == 1) ? W1 : W2;
    float v = W[k * 128 + nn];
    _Float16 hi = (_Float16)v;
    _Float16 lo = (_Float16)((v - (float)hi) * 1024.0f);
    int kk = k >> 5, quad = (k >> 3) & 3, j = k & 7;
    int t = nn >> 4, L = quad * 16 + (nn & 15);
    int off = ((kk * 8 + t) * 64 + L) * 8 + j;
    Wsw[(size_t)(w * 2 + 0) * 16384 + off] = hi;
    Wsw[(size_t)(w * 2 + 1) * 16384 + off] = lo;
}

// MFMA GEMM core (A fp16). Block: 4 waves, 64 rows; 8 col-tiles per wave.
__global__ __launch_bounds__(256) void gemm_mfma(const _Float16* __restrict__ A,
                                                 const _Float16* __restrict__ Wsw,
                                                 _Float16* __restrict__ C, int n) {
    __shared__ _Float16 Bl[2 * 16384];
    {
        const uint4* s = (const uint4*)Wsw;
        uint4* d = (uint4*)Bl;
        for (int i = threadIdx.x; i < 4096; i += 256) d[i] = s[i];
    }
    int wave = threadIdx.x >> 6, lane = threadIdx.x & 63;
    int quad = lane >> 4, mcol = lane & 15;
    int row0 = blockIdx.x * 64 + wave * 16 + mcol;
    half8 af[4] = {};
    if (row0 < n) {
        const half8* Arow = (const half8*)(A + (size_t)row0 * DFEAT);
        af[0] = Arow[0 + quad];
        af[1] = Arow[4 + quad];
        af[2] = Arow[8 + quad];
        af[3] = Arow[12 + quad];
    }
    __syncthreads();
    floatx4 acch[8] = {};
    floatx4 accl[8] = {};
    const half8* Bh = (const half8*)Bl;
    const half8* Blo = (const half8*)(Bl + 16384);
    #pragma unroll
    for (int kk = 0; kk < 4; kk++) {
        #pragma unroll
        for (int t = 0; t < 8; t++) {
            half8 bh = Bh[(kk * 8 + t) * 64 + lane];
            acch[t] = __builtin_amdgcn_mfma_f32_16x16x32_f16(af[kk], bh, acch[t], 0, 0, 0);
            half8 bl = Blo[(kk * 8 + t) * 64 + lane];
            accl[t] = __builtin_amdgcn_mfma_f32_16x16x32_f16(af[kk], bl, accl[t], 0, 0, 0);
        }
    }
    int orow_base = blockIdx.x * 64 + wave * 16 + quad * 4;
    #pragma unroll
    for (int t = 0; t < 8; t++) {
        #pragma unroll
        for (int r = 0; r < 4; r++) {
            int orow = orow_base + r;
            if (orow < n) {
                float v = acch[t][r] + accl[t][r] * (1.0f / 1024.0f);
                C[(size_t)orow * DFEAT + t * 16 + mcol] = (_Float16)v;
            }
        }
    }
}

// Same, but reads fp32 A (layer 0: x directly, no convert pass).
__global__ __launch_bounds__(256) void gemm_mfma_f32(const float* __restrict__ A,
                                                     const _Float16* __restrict__ Wsw,
                                                     _Float16* __restrict__ C, int n) {
    __shared__ _Float16 Bl[2 * 16384];
    {
        const uint4* s = (const uint4*)Wsw;
        uint4* d = (uint4*)Bl;
        for (int i = threadIdx.x; i < 4096; i += 256) d[i] = s[i];
    }
    int wave = threadIdx.x >> 6, lane = threadIdx.x & 63;
    int quad = lane >> 4, mcol = lane & 15;
    int row0 = blockIdx.x * 64 + wave * 16 + mcol;
    half8 af[4] = {};
    if (row0 < n) {
        const float4* Arow = (const float4*)(A + (size_t)row0 * DFEAT);
        #pragma unroll
        for (int kk = 0; kk < 4; kk++) {
            float4 f0 = Arow[kk * 8 + quad * 2];
            float4 f1 = Arow[kk * 8 + quad * 2 + 1];
            half8 a;
            a[0] = (_Float16)f0.x; a[1] = (_Float16)f0.y;
            a[2] = (_Float16)f0.z; a[3] = (_Float16)f0.w;
            a[4] = (_Float16)f1.x; a[5] = (_Float16)f1.y;
            a[6] = (_Float16)f1.z; a[7] = (_Float16)f1.w;
            af[kk] = a;
        }
    }
    __syncthreads();
    floatx4 acch[8] = {};
    floatx4 accl[8] = {};
    const half8* Bh = (const half8*)Bl;
    const half8* Blo = (const half8*)(Bl + 16384);
    #pragma unroll
    for (int kk = 0; kk < 4; kk++) {
        #pragma unroll
        for (int t = 0; t < 8; t++) {
            half8 bh = Bh[(kk * 8 + t) * 64 + lane];
            acch[t] = __builtin_amdgcn_mfma_f32_16x16x32_f16(af[kk], bh, acch[t], 0, 0, 0);
            half8 bl = Blo[(kk * 8 + t) * 64 + lane];
            accl[t] = __builtin_amdgcn_mfma_f32_16x16x32_f16(af[kk], bl, accl[t], 0, 0, 0);
        }
    }
    int orow_base = blockIdx.x * 64 + wave * 16 + quad * 4;
    #pragma unroll
    for (int t = 0; t < 8; t++) {
        #pragma unroll
        for (int r = 0; r < 4; r++) {
            int orow = orow_base + r;
            if (orow < n) {
                float v = acch[t][r] + accl[t][r] * (1.0f / 1024.0f);
                C[(size_t)orow * DFEAT + t * 16 + mcol] = (_Float16)v;
            }
        }
    }
}

// 4 nodes per 256-thread block (one wave each). Two 32-lane halves process
// alternate edges; lane covers 4 features (8B dwordx2 gathers). Cross-half
// shfl_xor reduction; half 0 writes.
__global__ __launch_bounds__(256) void agg_k(const _Float16* __restrict__ xw,
                                             const int* __restrict__ row_ptr,
                                             const int2* __restrict__ csr,
                                             const float* __restrict__ dinv,
                                             const float* __restrict__ bias,
                                             _Float16* __restrict__ out, int relu, int n) {
    int node = blockIdx.x * 4 + (threadIdx.x >> 6);
    if (node >= n) return;
    int lane = threadIdx.x & 63;
    int hf = lane >> 5;          // which edge of each pair
    int fl = lane & 31;          // features [fl*4, fl*4+4)
    const _Float16* base = xw + fl * 4;
    float a0 = 0.f, a1 = 0.f, a2 = 0.f, a3 = 0.f;
    // self-loop term (half 0 only; half 1 gets weight 0)
    {
        float di = dinv[node];
        float sw = (hf == 0) ? di * di : 0.f;
        uint2 r = *(const uint2*)(base + (size_t)node * DFEAT);
        float2 f0 = __half22float2(*(__half2*)&r.x);
        float2 f1 = __half22float2(*(__half2*)&r.y);
        a0 = sw * f0.x; a1 = sw * f0.y; a2 = sw * f1.x; a3 = sw * f1.y;
    }
    int e = row_ptr[node], end = row_ptr[node + 1];
    for (; e + 8 <= end; e += 8) {
        int2 c0 = csr[e + 0 + hf];
        int2 c1 = csr[e + 2 + hf];
        int2 c2 = csr[e + 4 + hf];
        int2 c3 = csr[e + 6 + hf];
        uint2 r0 = *(const uint2*)(base + (size_t)c0.x * DFEAT);
        uint2 r1 = *(const uint2*)(base + (size_t)c1.x * DFEAT);
        uint2 r2 = *(const uint2*)(base + (size_t)c2.x * DFEAT);
        uint2 r3 = *(const uint2*)(base + (size_t)c3.x * DFEAT);
        float w0 = __int_as_float(c0.y), w1 = __int_as_float(c1.y);
        float w2 = __int_as_float(c2.y), w3 = __int_as_float(c3.y);
        #define ACC(R, W)                                              \
        {                                                              \
            float2 f0 = __half22float2(*(__half2*)&R.x);               \
            float2 f1 = __half22float2(*(__half2*)&R.y);               \
            a0 = fmaf(W, f0.x, a0); a1 = fmaf(W, f0.y, a1);            \
            a2 = fmaf(W, f1.x, a2); a3 = fmaf(W, f1.y, a3);            \
        }
        ACC(r0, w0) ACC(r1, w1) ACC(r2, w2) ACC(r3, w3)
    }
    for (; e < end; e += 2) {
        int ee = e + hf;
        int s = 0; float w = 0.f;
        if (ee < end) { int2 c = csr[ee]; s = c.x; w = __int_as_float(c.y); }
        uint2 r = *(const uint2*)(base + (size_t)s * DFEAT);
        ACC(r, w)
    }
    #undef ACC
    // combine halves
    a0 += __shfl_xor(a0, 32, 64);
    a1 += __shfl_xor(a1, 32, 64);
    a2 += __shfl_xor(a2, 32, 64);
    a3 += __shfl_xor(a3, 32, 64);
    if (hf == 0) {
        float4 bv = *(const float4*)(bias + fl * 4);
        a0 += bv.x; a1 += bv.y; a2 += bv.z; a3 += bv.w;
        if (relu) {
            a0 = fmaxf(a0, 0.f); a1 = fmaxf(a1, 0.f);
            a2 = fmaxf(a2, 0.f); a3 = fmaxf(a3, 0.f);
        }
        __half2 o0 = __floats2half2_rn(a0, a1);
        __half2 o1 = __floats2half2_rn(a2, a3);
        uint2 st; st.x = *(unsigned*)&o0; st.y = *(unsigned*)&o1;
        *(uint2*)(out + (size_t)node * DFEAT + fl * 4) = st;
    }
}

// batch is sorted: chunk of 64 nodes per block, 128 threads (one per feature).
__global__ __launch_bounds__(128) void pool_k(const __half* __restrict__ h,
                                              const int* __restrict__ batch,
                                              float* __restrict__ out,
                                              float* __restrict__ pool_cnt, int n) {
    int j = threadIdx.x;
    int start = blockIdx.x * 64;
    if (start >= n) return;
    int end = start + 64; if (end > n) end = n;
    int g = batch[start];
    float acc = 0.f;
    float ccnt = 0.f;
    for (int i = start; i < end; i++) {
        int bi = batch[i];
        if (bi != g) {
            atomicAdd(&out[g * DFEAT + j], acc);
            if (j == 0) atomicAdd(&pool_cnt[g], ccnt);
            acc = 0.f; ccnt = 0.f; g = bi;
        }
        acc += __half2float(h[(size_t)i * DFEAT + j]);
        ccnt += 1.f;
    }
    atomicAdd(&out[g * DFEAT + j], acc);
    if (j == 0) atomicAdd(&pool_cnt[g], ccnt);
}

__global__ void div_k(float* __restrict__ out, const float* __restrict__ cnt) {
    int idx = blockIdx.x * 256 + threadIdx.x;
    if (idx < 64 * DFEAT) {
        float c = cnt[idx >> 7];
        out[idx] = out[idx] / fmaxf(c, 1.0f);
    }
}

extern "C" void kernel_launch(void* const* d_in, const int* in_sizes, int n_in,
                              void* d_out, int out_size, void* d_ws, size_t ws_size,
                              hipStream_t stream) {
    const float* x    = (const float*)d_in[0];
    const int*  eidx  = (const int*)d_in[1];
    const float* ew   = (const float*)d_in[2];
    const int*  batch = (const int*)d_in[3];
    const float* W0 = (const float*)d_in[4];
    const float* b0 = (const float*)d_in[5];
    const float* W1 = (const float*)d_in[6];
    const float* b1 = (const float*)d_in[7];
    const float* W2 = (const float*)d_in[8];
    const float* b2 = (const float*)d_in[9];
    float* out = (float*)d_out;

    const int N = in_sizes[0] / DFEAT;   // 50000 (must be <= 65536)
    const int E = in_sizes[2];           // 1600000
    const int* src = eidx;
    const int* dst = eidx + E;

    const int nbuck = (N + 255) / 256;           // 196
    const int nblk  = (E + BLK_E - 1) / BLK_E;   // 391
    const int total = nbuck * nblk;
    const int n_scan = total + 1;                // sentinel -> E

    size_t off = 0;
    auto walloc = [&](size_t bytes) -> void* {
        void* p = (char*)d_ws + off;
        off += (bytes + 255) & ~(size_t)255;
        return p;
    };
    float*   dinv    = (float*)  walloc((size_t)N * 4);
    int*     row_ptr = (int*)    walloc((size_t)(N + 1) * 4);
    int*     offs    = (int*)    walloc((size_t)n_scan * 4);
    int*     blksum  = (int*)    walloc(256 * 4);
    uint2*   rec     = (uint2*)  walloc((size_t)E * 8);
    uint2*   csr     = (uint2*)  walloc((size_t)E * 8);
    _Float16* xwH    = (_Float16*)walloc((size_t)N * DFEAT * 2);
    _Float16* hH     = (_Float16*)walloc((size_t)N * DFEAT * 2);
    _Float16* Wsw    = (_Float16*)walloc((size_t)6 * 16384 * 2);
    float*   pool_cnt= (float*)  walloc(64 * 4);

    hipMemsetAsync(out, 0, (size_t)64 * DFEAT * 4, stream);
    hipMemsetAsync(pool_cnt, 0, 64 * 4, stream);

    // ---- CSR build (no global atomics) ----
    hist_k<<<nblk, 256, 0, stream>>>(dst, offs, E, nblk, nbuck);
    int nsb = (n_scan + 1023) / 1024;
    scanb_k<<<nsb, 256, 0, stream>>>(offs, blksum, total, n_scan);
    scan_small256<<<1, 256, 0, stream>>>(blksum, nsb);
    scat_k<<<nblk, 256, 0, stream>>>(src, dst, ew, offs, blksum, rec, E, nblk, nbuck);
    bucket_k<<<nbuck, 1024, 0, stream>>>(rec, offs, blksum, dinv, row_ptr, csr, N, nblk);
    normfix_k<<<(E + 255) / 256, 256, 0, stream>>>(csr, dinv, row_ptr, E, N);

    wconv_k<<<(3 * 16384 + 255) / 256, 256, 0, stream>>>(W0, W1, W2, Wsw);

    int gG = (N + 63) / 64;
    int gA = (N + 3) / 4;
    // layer 0 (reads fp32 x directly)
    gemm_mfma_f32<<<gG, 256, 0, stream>>>(x, Wsw + (size_t)0 * 32768, xwH, N);
    agg_k<<<gA, 256, 0, stream>>>(xwH, row_ptr, (const int2*)csr, dinv, b0, hH, 1, N);
    // layer 1
    gemm_mfma<<<gG, 256, 0, stream>>>(hH, Wsw + (size_t)1 * 32768, xwH, N);
    agg_k<<<gA, 256, 0, stream>>>(xwH, row_ptr, (const int2*)csr, dinv, b1, hH, 1, N);
    // layer 2
    gemm_mfma<<<gG, 256, 0, stream>>>(hH, Wsw + (size_t)2 * 32768, xwH, N);
    agg_k<<<gA, 256, 0, stream>>>(xwH, row_ptr, (const int2*)csr, dinv, b2, hH, 0, N);

    pool_k<<<(N + 63) / 64, 128, 0, stream>>>((const __half*)hH, batch, out, pool_cnt, N);
    div_k<<<32, 256, 0, stream>>>(out, pool_cnt);
}